// Round 5
// baseline (348.873 us; speedup 1.0000x reference)
//
#include <hip/hip_runtime.h>
#include <hip/hip_bf16.h>
#include <math.h>

// Problem constants: B=4, D=1024, N=2048, K=1024, fp32 in/out.
#define BB 4
#define DD 1024
#define NN 2048
#define KK 1024
#define NT128 16            // NN/128
#define NTRI 136            // 16*17/2 lower-triangular 128x128 tiles
#define TRI_ELEMS 16384     // 128*128

typedef __attribute__((ext_vector_type(4))) float f32x4;
typedef __attribute__((ext_vector_type(8))) short bfrag;

typedef __attribute__((address_space(1))) const unsigned int gu32;
typedef __attribute__((address_space(3))) unsigned int lu32;

// async global->LDS, 16B per lane; LDS dest = base + lane*16 (wave-uniform base)
__device__ __forceinline__ void async16(const void* g, void* l) {
  __builtin_amdgcn_global_load_lds((gu32*)g, (lu32*)l, 16, 0, 0);
}

__device__ __forceinline__ ushort f2b(float f) {  // fp32 -> bf16 RNE
  union { float f; unsigned u; } c; c.f = f;
  unsigned u = c.u + 0x7fffu + ((c.u >> 16) & 1u);
  return (ushort)(u >> 16);
}
__device__ __forceinline__ float b2f(ushort h) {
  union { unsigned u; float f; } c; c.u = ((unsigned)h) << 16;
  return c.f;
}

// ---------------------------------------------------------------------------
// prep: merged input transform, grid (64, 32, 6), block (32,8).
//  z<4 : x [b=z][d][n] fp32 -> x_hi (bf16 same layout), xT hi/lo ([b][n][d])
//  z>=4: weight w = (z-4)*2 + (bx>>5): W (K x D, [k][d]) -> WT [d][k] bf16
//        (WQ, WK split hi+lo; WV, WO hi only)
// ---------------------------------------------------------------------------
__global__ __launch_bounds__(256) void prep(
    const float* __restrict__ x,
    const float* __restrict__ WQ, const float* __restrict__ WK,
    const float* __restrict__ WV, const float* __restrict__ WO,
    ushort* __restrict__ xhi, ushort* __restrict__ xTh, ushort* __restrict__ xTl,
    ushort* __restrict__ qh, ushort* __restrict__ ql,
    ushort* __restrict__ kh, ushort* __restrict__ kl_,
    ushort* __restrict__ vh, ushort* __restrict__ oh) {
  const int z = blockIdx.z;
  const int tx = threadIdx.x, ty = threadIdx.y;
  __shared__ float tile[32][33];
  if (z < 4) {
    const int b = z;
    const int n0 = blockIdx.x * 32, d0 = blockIdx.y * 32;
    const float* xb = x + (long)b * DD * NN;
    ushort* xhb = xhi + (long)b * DD * NN;
#pragma unroll
    for (int r = 0; r < 4; ++r) {
      const int dl = ty + r * 8;
      const float v = xb[(long)(d0 + dl) * NN + n0 + tx];
      tile[dl][tx] = v;
      xhb[(long)(d0 + dl) * NN + n0 + tx] = f2b(v);
    }
    __syncthreads();
#pragma unroll
    for (int r = 0; r < 4; ++r) {
      const int nl = ty + r * 8;
      const float v = tile[tx][nl];
      const ushort h = f2b(v);
      const long o = (long)b * NN * DD + (long)(n0 + nl) * DD + d0 + tx;
      xTh[o] = h;
      xTl[o] = f2b(v - b2f(h));
    }
  } else {
    const int w = (z - 4) * 2 + (blockIdx.x >> 5);
    const float* W = (w == 0) ? WQ : (w == 1) ? WK : (w == 2) ? WV : WO;
    ushort* Th = (w == 0) ? qh : (w == 1) ? kh : (w == 2) ? vh : oh;
    ushort* Tl = (w == 0) ? ql : (w == 1) ? kl_ : nullptr;
    const int k0 = (blockIdx.x & 31) * 32, d0 = blockIdx.y * 32;
#pragma unroll
    for (int r = 0; r < 4; ++r) {
      const int kl = ty + r * 8;
      tile[kl][tx] = W[(long)(k0 + kl) * DD + d0 + tx];
    }
    __syncthreads();
#pragma unroll
    for (int r = 0; r < 4; ++r) {
      const int dl = ty + r * 8;
      const float v = tile[tx][dl];              // = W[k0+tx][d0+dl]
      const ushort h = f2b(v);
      const long o = (long)(d0 + dl) * KK + k0 + tx;
      Th[o] = h;
      if (Tl) Tl[o] = f2b(v - b2f(h));
    }
  }
}

// ---------------------------------------------------------------------------
// Merged weight-product GEMM, 64x64 tiles, BK=32, 512 blocks:
//   id<256 : Mqk[m,n] = sum_k wqT[m,k] wkT[n,k]  (split 3-MFMA, split store)
//   id>=256: Mov[m,n] = sum_k woT[m,k] wvT[n,k]  (plain bf16)
// ---------------------------------------------------------------------------
__global__ __launch_bounds__(256) void gemm_w(
    const ushort* __restrict__ qh, const ushort* __restrict__ ql,
    const ushort* __restrict__ kh, const ushort* __restrict__ kl_,
    const ushort* __restrict__ vh, const ushort* __restrict__ oh,
    ushort* __restrict__ mqk_h, ushort* __restrict__ mqk_l,
    ushort* __restrict__ mov_h) {
  extern __shared__ ushort smem[];
  ushort* sAh = smem;            // [64][32] 4KB
  ushort* sAl = smem + 2048;
  ushort* sBh = smem + 4096;
  ushort* sBl = smem + 6144;

  const int id = blockIdx.x;
  const int half = id >> 8;                  // 0 = Mqk (split), 1 = Mov (plain)
  const int t = id & 255;
  const int m0 = (t >> 4) * 64, n0 = (t & 15) * 64;
  const ushort* A_h = half ? oh : qh;
  const ushort* B_h = half ? vh : kh;

  const int tid = threadIdx.x;
  const int lane = tid & 63, wave = tid >> 6;
  const int wm = (wave & 1) * 32, wn = (wave >> 1) * 32;
  const int r16 = lane & 15, quad = lane >> 4;
  const int kc = ((lane & 3) ^ ((lane >> 3) & 3)) * 8;   // swizzled k-chunk
  const int srow = lane >> 2;

  f32x4 acc[2][2];
#pragma unroll
  for (int i = 0; i < 2; ++i)
#pragma unroll
    for (int j = 0; j < 2; ++j) acc[i][j] = (f32x4){0.f, 0.f, 0.f, 0.f};

  for (int k0 = 0; k0 < KK; k0 += 32) {
    __syncthreads();
    {
      const int row = wave * 16 + srow;
      const long aoff = (long)(m0 + row) * KK + k0 + kc;
      const long boff = (long)(n0 + row) * KK + k0 + kc;
      async16(A_h + aoff, sAh + wave * 512);
      async16(B_h + boff, sBh + wave * 512);
      if (half == 0) {
        async16(ql + aoff, sAl + wave * 512);
        async16(kl_ + boff, sBl + wave * 512);
      }
    }
    __syncthreads();

    const int sw = (r16 >> 1) & 3;
    bfrag ah[2], bh[2], al[2], bl[2];
#pragma unroll
    for (int t2 = 0; t2 < 2; ++t2) {
      ah[t2] = *(const bfrag*)&sAh[(wm + t2 * 16 + r16) * 32 + (quad ^ sw) * 8];
      bh[t2] = *(const bfrag*)&sBh[(wn + t2 * 16 + r16) * 32 + (quad ^ sw) * 8];
      if (half == 0) {
        al[t2] = *(const bfrag*)&sAl[(wm + t2 * 16 + r16) * 32 + (quad ^ sw) * 8];
        bl[t2] = *(const bfrag*)&sBl[(wn + t2 * 16 + r16) * 32 + (quad ^ sw) * 8];
      }
    }
#pragma unroll
    for (int mt = 0; mt < 2; ++mt)
#pragma unroll
      for (int nt = 0; nt < 2; ++nt) {
        acc[mt][nt] = __builtin_amdgcn_mfma_f32_16x16x32_bf16(ah[mt], bh[nt], acc[mt][nt], 0, 0, 0);
        if (half == 0) {
          acc[mt][nt] = __builtin_amdgcn_mfma_f32_16x16x32_bf16(ah[mt], bl[nt], acc[mt][nt], 0, 0, 0);
          acc[mt][nt] = __builtin_amdgcn_mfma_f32_16x16x32_bf16(al[mt], bh[nt], acc[mt][nt], 0, 0, 0);
        }
      }
  }

#pragma unroll
  for (int mt = 0; mt < 2; ++mt)
#pragma unroll
    for (int nt = 0; nt < 2; ++nt)
#pragma unroll
      for (int reg = 0; reg < 4; ++reg) {
        const int ml = wm + mt * 16 + quad * 4 + reg;
        const int nl = wn + nt * 16 + r16;
        const float v = acc[mt][nt][reg];
        const long o = (long)(m0 + ml) * DD + n0 + nl;
        if (half == 0) {
          const ushort h = f2b(v);
          mqk_h[o] = h;
          mqk_l[o] = f2b(v - b2f(h));
        } else {
          mov_h[o] = f2b(v);
        }
      }
}

// ---------------------------------------------------------------------------
// bf16 MFMA GEMM, 4 waves, 16x16x32 MFMA, R4 recipe schedule (dbuf, stage
// issued BEFORE compute, ONE vmcnt(0)+barrier per tile AFTER the MFMAs).
//
// OCCUPANCY is the R5 change: five schedule variants all pinned at ~76us
// with <=2 blocks/CU (<=2 waves/SIMD, Occupancy ~12%). Split tiles shrink
// 128x128 -> 128x64 so LDS/buffer = A 16KB + B 8KB = 24KB, dbuf 48KB ->
// 3 blocks/CU = 12 waves/CU (m97's regime, m114 cross-wave overlap), with
// grids 1024/1088 supplying the blocks.
//
// SPLIT=1: BK=32, hi|lo packed per 128B row (chunks 0-3 = hi k, 4-7 = lo),
//   proven ^(row&7) chunk swizzle (R2-R4: 0 conflicts). Staging pre-swizzles
//   the per-lane GLOBAL source (LDS dest linear, m104/m173). Tile 128x64,
//   per-wave 64x32 (acc[4][2], 24 MFMA + 12 ds_read/tile).
// SPLIT=0: BK=64, tile 128x128, per-wave 64x64 (unchanged from R4).
// Fragment layouts (HW-verified, learn_hip m89):
//   A[m=lane&15][k=quad*8+j], B[n=lane&15][k=quad*8+j],
//   C/D: col=lane&15, row=quad*4+reg.
// TRIA : A staged from triangular tile layout; K limited to m0+128.
// SWIZ : XCD-locality block mapping (assumes xcd = blockIdx.x % 8):
//   1: 1024 blocks (step 2): g=(blk&7)*128+(blk>>3); P=g>>4 -> b=P>>4,
//      m0=(P&15)*128; n0=(g&15)*64.
//   2: 1088 blocks (step 3 tri, = 8*136): g=(blk&7)*136+(blk>>3);
//      b=g/272, r=g%272, t=r>>1, nh=r&1; decode (ti,tj); m0=ti*128,
//      n0=tj*128+nh*64.
//   3: 512 blocks, causal-balanced: XCD x owns mtiles {x, 15-x}
//   4: 512 blocks, swapped roles (M=8 d-tiles, N=16 i-tiles)
// STORE 0: split bf16 (C0=hi, C1=lo); 1: tri fp32; 2: bf16; 3: fp32 + Res.
// ---------------------------------------------------------------------------
template <int SPLIT, int TRIA, int STORE, int SWIZ>
__global__ __launch_bounds__(256) void gemm_mfma(
    const ushort* __restrict__ Ah, const ushort* __restrict__ Al,
    const ushort* __restrict__ Bh, const ushort* __restrict__ Bl,
    void* __restrict__ C0, void* __restrict__ C1, const float* __restrict__ Res,
    int K, int lda, int ldb, int ldc,
    long bA, long bB, long bC, long bR) {
  extern __shared__ ushort smem[];
  constexpr int BN   = SPLIT ? 64 : 128;     // B-tile rows
  constexpr int NFR  = SPLIT ? 2 : 4;        // per-wave n-frags
  constexpr int BUFS = 8192 + BN * 64;       // ushorts per pipeline buffer

  int b, m0, n0, tiC = 0;
  if (SWIZ == 2) {
    const int g = (blockIdx.x & 7) * 136 + (blockIdx.x >> 3);
    b = g / 272;
    const int r = g - b * 272;
    const int t = r >> 1, nh = r & 1;
    int ti = 0;
    while ((ti + 1) * (ti + 2) / 2 <= t) ++ti;
    const int tj = t - ti * (ti + 1) / 2;
    m0 = ti * 128; n0 = tj * 128 + nh * 64; tiC = t;
  } else if (SWIZ == 1) {
    const int g = (blockIdx.x & 7) * 128 + (blockIdx.x >> 3);
    const int P = g >> 4;
    b = P >> 4;
    m0 = (P & 15) * 128;
    n0 = (g & 15) * 64;
  } else if (SWIZ == 3) {
    const int xcd = blockIdx.x & 7;
    const int idx = blockIdx.x >> 3;      // [0,64)
    const int q = idx >> 3;               // [0,8)
    b = q >> 1;
    const int mt_ = (q & 1) ? (15 - xcd) : xcd;
    m0 = mt_ * 128;
    n0 = (idx & 7) * 128;
  } else {  // SWIZ == 4
    const int g = (blockIdx.x & 7) * 64 + (blockIdx.x >> 3);
    const int P = g >> 3;
    b = P >> 4;
    n0 = (P & 15) * 128;
    m0 = (g & 7) * 128;
  }
  const int kmax = TRIA ? (m0 + 128) : K;
  int triA0 = 0;
  if (TRIA) { const int ti = m0 >> 7; triA0 = ti * (ti + 1) / 2; }

  const ushort* A_h = Ah + (long)b * bA;
  const ushort* B_h = Bh + (long)b * bB;
  const ushort* A_l = SPLIT ? Al + (long)b * bA : nullptr;
  const ushort* B_l = SPLIT ? Bl + (long)b * bB : nullptr;

  const int tid = threadIdx.x;
  const int lane = tid & 63, wave = tid >> 6;
  const int wm = (wave & 1) * 64;
  const int wn = (wave >> 1) * (SPLIT ? 32 : 64);
  const int r16 = lane & 15, quad = lane >> 4;
  const int rk = r16 & 7;

  // staging lane mapping: 8 rows x 8 phys chunks per async16 (1KB)
  const int lrow = lane >> 3;                  // row within 8-row segment
  const int lc = (lane & 7) ^ lrow;            // logical chunk = phys ^ row&7
  // SPLIT: logical chunks 0-3 = hi k-chunks, 4-7 = lo k-chunks
  const int lckS = (lc & 3) * 8;
  const bool lo_src = lc >= 4;
  // plain: logical chunk = k-chunk of BK=64
  const int kcP = lc * 8;

  f32x4 acc[4][NFR];
#pragma unroll
  for (int i = 0; i < 4; ++i)
#pragma unroll
    for (int j = 0; j < NFR; ++j) acc[i][j] = (f32x4){0.f, 0.f, 0.f, 0.f};

  auto STAGE = [&](int db, int t) {
    ushort* dst = smem + db * BUFS;
    if (SPLIT) {
      const int k0 = t << 5;
      const ushort* baseA = lo_src ? A_l : A_h;
      const ushort* baseB = lo_src ? B_l : B_h;
#pragma unroll
      for (int s = 0; s < 4; ++s) {            // A: 16 segs / 4 waves
        const int seg = wave * 4 + s;          // [0,16)
        const int row = seg * 8 + lrow;        // [0,128)
        async16(baseA + (long)(m0 + row) * lda + k0 + lckS, dst + seg * 512);
      }
#pragma unroll
      for (int s = 0; s < 2; ++s) {            // B: 8 segs / 4 waves
        const int seg = wave * 2 + s;          // [0,8)
        const int row = seg * 8 + lrow;        // [0,64)
        async16(baseB + (long)(n0 + row) * ldb + k0 + lckS, dst + 8192 + seg * 512);
      }
    } else {
      const int k0 = t << 6;
#pragma unroll
      for (int s = 0; s < 4; ++s) {
        const int seg = wave * 4 + s;
        const int row = seg * 8 + lrow;
        long aoff;
        if (TRIA)
          aoff = (long)(triA0 + (k0 >> 7)) * TRI_ELEMS + (long)row * 128 + (k0 & 127) + kcP;
        else
          aoff = (long)(m0 + row) * lda + k0 + kcP;
        async16(A_h + aoff, dst + seg * 512);
        async16(B_h + (long)(n0 + row) * ldb + k0 + kcP, dst + 8192 + seg * 512);
      }
    }
  };

  const int T = kmax >> (SPLIT ? 5 : 6);
  STAGE(0, 0);
  asm volatile("s_waitcnt vmcnt(0)" ::: "memory");
  __builtin_amdgcn_s_barrier();
  __builtin_amdgcn_sched_barrier(0);

  for (int t = 0; t < T; ++t) {
    const int cur = t & 1;
    if (t + 1 < T) STAGE(cur ^ 1, t + 1);      // issue BEFORE compute
    const ushort* sA = smem + cur * BUFS;
    const ushort* sB = sA + 8192;

    if (SPLIT) {
      bfrag ah[4], al[4], bh[2], bl[2];
#pragma unroll
      for (int f = 0; f < 4; ++f) {
        const int arow = (wm + f * 16 + r16) * 64;
        ah[f] = *(const bfrag*)&sA[arow + (quad ^ rk) * 8];
        al[f] = *(const bfrag*)&sA[arow + ((quad + 4) ^ rk) * 8];
      }
#pragma unroll
      for (int f = 0; f < 2; ++f) {
        const int brow = (wn + f * 16 + r16) * 64;
        bh[f] = *(const bfrag*)&sB[brow + (quad ^ rk) * 8];
        bl[f] = *(const bfrag*)&sB[brow + ((quad + 4) ^ rk) * 8];
      }
      __builtin_amdgcn_s_setprio(1);
#pragma unroll
      for (int mt = 0; mt < 4; ++mt)
#pragma unroll
        for (int nt = 0; nt < 2; ++nt) {
          acc[mt][nt] = __builtin_amdgcn_mfma_f32_16x16x32_bf16(ah[mt], bh[nt], acc[mt][nt], 0, 0, 0);
          acc[mt][nt] = __builtin_amdgcn_mfma_f32_16x16x32_bf16(ah[mt], bl[nt], acc[mt][nt], 0, 0, 0);
          acc[mt][nt] = __builtin_amdgcn_mfma_f32_16x16x32_bf16(al[mt], bh[nt], acc[mt][nt], 0, 0, 0);
        }
      __builtin_amdgcn_s_setprio(0);
    } else {
#pragma unroll
      for (int ksub = 0; ksub < 2; ++ksub) {
        const int ch = ((ksub * 4 + quad) ^ rk) * 8;     // physical chunk
        bfrag a4[4], b4[4];
#pragma unroll
        for (int f = 0; f < 4; ++f) {
          a4[f] = *(const bfrag*)&sA[(wm + f * 16 + r16) * 64 + ch];
          b4[f] = *(const bfrag*)&sB[(wn + f * 16 + r16) * 64 + ch];
        }
        __builtin_amdgcn_s_setprio(1);
#pragma unroll
        for (int mt = 0; mt < 4; ++mt)
#pragma unroll
          for (int nt = 0; nt < 4; ++nt)
            acc[mt][nt] = __builtin_amdgcn_mfma_f32_16x16x32_bf16(a4[mt], b4[nt], acc[mt][nt], 0, 0, 0);
        __builtin_amdgcn_s_setprio(0);
      }
    }

    __builtin_amdgcn_sched_barrier(0);
    asm volatile("s_waitcnt vmcnt(0)" ::: "memory");   // t+1 loads landed
    __builtin_amdgcn_s_barrier();                      // buf[cur^1] ready
    __builtin_amdgcn_sched_barrier(0);
  }

  // epilogue
#pragma unroll
  for (int mt = 0; mt < 4; ++mt)
#pragma unroll
    for (int nt = 0; nt < NFR; ++nt)
#pragma unroll
      for (int reg = 0; reg < 4; ++reg) {
        const int ml = wm + mt * 16 + quad * 4 + reg;
        const int nl = wn + nt * 16 + r16;
        const float v = acc[mt][nt][reg];
        if (STORE == 0) {
          ushort* Ch = (ushort*)C0 + (long)b * bC;
          ushort* Cl = (ushort*)C1 + (long)b * bC;
          const long o = (long)(m0 + ml) * ldc + n0 + nl;
          const ushort h = f2b(v);
          Ch[o] = h;
          Cl[o] = f2b(v - b2f(h));
        } else if (STORE == 1) {
          float* C = (float*)C0 + (long)b * bC + (long)tiC * TRI_ELEMS;
          C[ml * 128 + (n0 & 127) + nl] = v;
        } else if (STORE == 2) {
          ushort* C = (ushort*)C0 + (long)b * bC;
          C[(long)(m0 + ml) * ldc + n0 + nl] = f2b(v);
        } else {
          float* C = (float*)C0 + (long)b * bC;
          const float* R = Res + (long)b * bR;
          const long o = (long)(m0 + ml) * ldc + n0 + nl;
          C[o] = R[o] + v;
        }
      }
}

// ---------------------------------------------------------------------------
// Causal softmax over triangular-tiled logits. One block per row (b, i).
// Writes bf16 A in tri layout, zero-filling diagonal-tile cols beyond i.
// ---------------------------------------------------------------------------
__global__ __launch_bounds__(256) void softmax_tri(
    const float* __restrict__ L, ushort* __restrict__ Aout) {
  const int row = blockIdx.x;
  const int b = row >> 11, i = row & (NN - 1);
  const int ti = i >> 7, ml = i & 127;
  const long base = (long)b * ((long)NTRI * TRI_ELEMS);
  const int trib = ti * (ti + 1) / 2;
  const int len = i + 1;
  const int tot = (ti + 1) * 128;
  const int tid = threadIdx.x;
  __shared__ float red[256];
  float vv[8];
  float m = -INFINITY;
#pragma unroll
  for (int u = 0; u < 8; ++u) {
    const int j = tid + u * 256;
    if (j < len) {
      const float v = L[base + (long)(trib + (j >> 7)) * TRI_ELEMS + ml * 128 + (j & 127)];
      vv[u] = v;
      m = fmaxf(m, v);
    }
  }
  red[tid] = m; __syncthreads();
  for (int s = 128; s; s >>= 1) { if (tid < s) red[tid] = fmaxf(red[tid], red[tid + s]); __syncthreads(); }
  m = red[0]; __syncthreads();
  float sum = 0.f;
#pragma unroll
  for (int u = 0; u < 8; ++u) {
    const int j = tid + u * 256;
    if (j < len) { const float e = __expf(vv[u] - m); vv[u] = e; sum += e; }
  }
  red[tid] = sum; __syncthreads();
  for (int s = 128; s; s >>= 1) { if (tid < s) red[tid] += red[tid + s]; __syncthreads(); }
  const float inv = 1.f / red[0];
#pragma unroll
  for (int u = 0; u < 8; ++u) {
    const int j = tid + u * 256;
    if (j < tot) {
      const ushort o = (j < len) ? f2b(vv[u] * inv) : (ushort)0;
      Aout[base + (long)(trib + (j >> 7)) * TRI_ELEMS + ml * 128 + (j & 127)] = o;
    }
  }
}

// ---------------------------------------------------------------------------
// Pipeline (all MFMA operands k-contiguous by construction):
//  0. prep: x -> x_hi, xT hi/lo; W_Q..W_O -> WT [d][k] bf16     (1 dispatch)
//  1. gemm_w: Mqk (split) + Mov (plain) in one 512-block dispatch
//  2. tT[i,d] = sum_e xT[i,e] Mqk[d,e]      split 128x64 tiles, SWIZ=1, 1024
//  3. logits[i,j] = sum_d xT[i,d] tT[j,d]   split 128x64, tri, SWIZ=2, 1088
//  4. A = causal softmax (bf16, tri layout, zero-padded diag tiles)
//  5. ctxT[i,e] = sum_{t<=i} A[i,t] x[e,t]  plain, causal K, SWIZ=3 (bal)
//  6. out[d,i] = x[d,i] + sum_e Mov[d,e] ctxT[i,e]   plain + res, SWIZ=4
// ---------------------------------------------------------------------------
extern "C" void kernel_launch(void* const* d_in, const int* in_sizes, int n_in,
                              void* d_out, int out_size, void* d_ws, size_t ws_size,
                              hipStream_t stream) {
  const float* x = (const float*)d_in[0];
  const float* WQ = (const float*)d_in[1];
  const float* WK = (const float*)d_in[2];
  const float* WV = (const float*)d_in[3];
  const float* WO = (const float*)d_in[4];
  float* out = (float*)d_out;

  const long XE = (long)BB * DD * NN;    // 8M elements
  const long WE = (long)DD * KK;         // 1M elements
  ushort* x_hi = (ushort*)d_ws;
  ushort* xTh = x_hi + XE;
  ushort* xTl = xTh + XE;
  ushort* wqT_h = xTl + XE;
  ushort* wqT_l = wqT_h + WE;
  ushort* wkT_h = wqT_l + WE;
  ushort* wkT_l = wkT_h + WE;
  ushort* wvT_h = wkT_l + WE;
  ushort* woT_h = wvT_h + WE;
  ushort* mqk_h = woT_h + WE;
  ushort* mqk_l = mqk_h + WE;
  ushort* mov_h = mqk_l + WE;
  ushort* tTh = mov_h + WE;
  ushort* tTl = tTh + XE;
  float* logits = (float*)(tTl + XE);    // B*NTRI*TRI_ELEMS fp32 (~35.7MB)
  ushort* A_tri = tTh;                   // overlays tT hi+lo (dead after step 3)
  ushort* ctxT = (ushort*)logits;        // overlays logits (dead after softmax)
  const long TRIB = (long)NTRI * TRI_ELEMS;
  const long XB = XE / BB;

  prep<<<dim3(64, 32, 6), dim3(32, 8), 0, stream>>>(
      x, WQ, WK, WV, WO, x_hi, xTh, xTl,
      wqT_h, wqT_l, wkT_h, wkT_l, wvT_h, woT_h);

  // Mqk (split) + Mov (plain), merged 64-tile dispatch
  gemm_w<<<dim3(512), 256, 16384, stream>>>(
      wqT_h, wqT_l, wkT_h, wkT_l, wvT_h, woT_h, mqk_h, mqk_l, mov_h);

  // tT = xT * Mqk^T (split, 128x64 tiles, 48KB dbuf -> 3 blocks/CU)
  gemm_mfma<1, 0, 0, 1><<<dim3(1024), 256, 49152, stream>>>(
      xTh, xTl, mqk_h, mqk_l, tTh, tTl, nullptr,
      DD, DD, DD, DD, XB, 0, XB, 0);

  // logits (lower tri, split 128x64 tiles, 1088 = 8*136 blocks)
  gemm_mfma<1, 0, 1, 2><<<dim3(1088), 256, 49152, stream>>>(
      xTh, xTl, tTh, tTl, logits, nullptr, nullptr,
      DD, DD, DD, 0, XB, XB, TRIB, 0);

  softmax_tri<<<dim3(BB * NN), 256, 0, stream>>>(logits, A_tri);

  // ctxT = A * x^T (tri A, causal K-limit, balanced XCD swizzle, dbuf)
  gemm_mfma<0, 1, 2, 3><<<dim3(512), 256, 65536, stream>>>(
      A_tri, nullptr, x_hi, nullptr, ctxT, nullptr, nullptr,
      NN, 0, NN, DD, TRIB, XB, XB, 0);

  // out = x + Mov * ctx (SWIZ=4: M=8 d-tiles, N=16 i-tiles, dbuf)
  gemm_mfma<0, 0, 3, 4><<<dim3(512), 256, 65536, stream>>>(
      mov_h, nullptr, ctxT, nullptr, out, nullptr, x,
      DD, DD, DD, NN, 0, XB, XB, XB);
}

// Round 6
// 344.506 us; speedup vs baseline: 1.0127x; 1.0127x over previous
//
#include <hip/hip_runtime.h>
#include <hip/hip_bf16.h>
#include <math.h>

// Problem constants: B=4, D=1024, N=2048, K=1024, fp32 in/out.
#define BB 4
#define DD 1024
#define NN 2048
#define KK 1024
#define NT128 16            // NN/128
#define NTRI 136            // 16*17/2 lower-triangular 128x128 tiles
#define TRI_ELEMS 16384     // 128*128

typedef __attribute__((ext_vector_type(4))) float f32x4;
typedef __attribute__((ext_vector_type(16))) float f32x16;
typedef __attribute__((ext_vector_type(8))) short bfrag;

typedef __attribute__((address_space(1))) const unsigned int gu32;
typedef __attribute__((address_space(3))) unsigned int lu32;

// async global->LDS, 16B per lane; LDS dest = base + lane*16 (wave-uniform base)
__device__ __forceinline__ void async16(const void* g, void* l) {
  __builtin_amdgcn_global_load_lds((gu32*)g, (lu32*)l, 16, 0, 0);
}

__device__ __forceinline__ ushort f2b(float f) {  // fp32 -> bf16 RNE
  union { float f; unsigned u; } c; c.f = f;
  unsigned u = c.u + 0x7fffu + ((c.u >> 16) & 1u);
  return (ushort)(u >> 16);
}
__device__ __forceinline__ float b2f(ushort h) {
  union { unsigned u; float f; } c; c.u = ((unsigned)h) << 16;
  return c.f;
}

// ---------------------------------------------------------------------------
// prep: merged input transform, grid (64, 32, 6), block (32,8).
//  z<4 : x [b=z][d][n] fp32 -> x_hi (bf16 same layout), xT hi/lo ([b][n][d])
//  z>=4: weight w = (z-4)*2 + (bx>>5): W (K x D, [k][d]) -> WT [d][k] bf16
//        (WQ, WK split hi+lo; WV, WO hi only)
// ---------------------------------------------------------------------------
__global__ __launch_bounds__(256) void prep(
    const float* __restrict__ x,
    const float* __restrict__ WQ, const float* __restrict__ WK,
    const float* __restrict__ WV, const float* __restrict__ WO,
    ushort* __restrict__ xhi, ushort* __restrict__ xTh, ushort* __restrict__ xTl,
    ushort* __restrict__ qh, ushort* __restrict__ ql,
    ushort* __restrict__ kh, ushort* __restrict__ kl_,
    ushort* __restrict__ vh, ushort* __restrict__ oh) {
  const int z = blockIdx.z;
  const int tx = threadIdx.x, ty = threadIdx.y;
  __shared__ float tile[32][33];
  if (z < 4) {
    const int b = z;
    const int n0 = blockIdx.x * 32, d0 = blockIdx.y * 32;
    const float* xb = x + (long)b * DD * NN;
    ushort* xhb = xhi + (long)b * DD * NN;
#pragma unroll
    for (int r = 0; r < 4; ++r) {
      const int dl = ty + r * 8;
      const float v = xb[(long)(d0 + dl) * NN + n0 + tx];
      tile[dl][tx] = v;
      xhb[(long)(d0 + dl) * NN + n0 + tx] = f2b(v);
    }
    __syncthreads();
#pragma unroll
    for (int r = 0; r < 4; ++r) {
      const int nl = ty + r * 8;
      const float v = tile[tx][nl];
      const ushort h = f2b(v);
      const long o = (long)b * NN * DD + (long)(n0 + nl) * DD + d0 + tx;
      xTh[o] = h;
      xTl[o] = f2b(v - b2f(h));
    }
  } else {
    const int w = (z - 4) * 2 + (blockIdx.x >> 5);
    const float* W = (w == 0) ? WQ : (w == 1) ? WK : (w == 2) ? WV : WO;
    ushort* Th = (w == 0) ? qh : (w == 1) ? kh : (w == 2) ? vh : oh;
    ushort* Tl = (w == 0) ? ql : (w == 1) ? kl_ : nullptr;
    const int k0 = (blockIdx.x & 31) * 32, d0 = blockIdx.y * 32;
#pragma unroll
    for (int r = 0; r < 4; ++r) {
      const int kl = ty + r * 8;
      tile[kl][tx] = W[(long)(k0 + kl) * DD + d0 + tx];
    }
    __syncthreads();
#pragma unroll
    for (int r = 0; r < 4; ++r) {
      const int dl = ty + r * 8;
      const float v = tile[tx][dl];              // = W[k0+tx][d0+dl]
      const ushort h = f2b(v);
      const long o = (long)(d0 + dl) * KK + k0 + tx;
      Th[o] = h;
      if (Tl) Tl[o] = f2b(v - b2f(h));
    }
  }
}

// ---------------------------------------------------------------------------
// Merged weight-product GEMM, 64x64 tiles, BK=32, 512 blocks:
//   id<256 : Mqk[m,n] = sum_k wqT[m,k] wkT[n,k]  (split 3-MFMA, split store)
//   id>=256: Mov[m,n] = sum_k woT[m,k] wvT[n,k]  (plain bf16)
// ---------------------------------------------------------------------------
__global__ __launch_bounds__(256) void gemm_w(
    const ushort* __restrict__ qh, const ushort* __restrict__ ql,
    const ushort* __restrict__ kh, const ushort* __restrict__ kl_,
    const ushort* __restrict__ vh, const ushort* __restrict__ oh,
    ushort* __restrict__ mqk_h, ushort* __restrict__ mqk_l,
    ushort* __restrict__ mov_h) {
  extern __shared__ ushort smem[];
  ushort* sAh = smem;            // [64][32] 4KB
  ushort* sAl = smem + 2048;
  ushort* sBh = smem + 4096;
  ushort* sBl = smem + 6144;

  const int id = blockIdx.x;
  const int half = id >> 8;                  // 0 = Mqk (split), 1 = Mov (plain)
  const int t = id & 255;
  const int m0 = (t >> 4) * 64, n0 = (t & 15) * 64;
  const ushort* A_h = half ? oh : qh;
  const ushort* B_h = half ? vh : kh;

  const int tid = threadIdx.x;
  const int lane = tid & 63, wave = tid >> 6;
  const int wm = (wave & 1) * 32, wn = (wave >> 1) * 32;
  const int r16 = lane & 15, quad = lane >> 4;
  const int kc = ((lane & 3) ^ ((lane >> 3) & 3)) * 8;   // swizzled k-chunk
  const int srow = lane >> 2;

  f32x4 acc[2][2];
#pragma unroll
  for (int i = 0; i < 2; ++i)
#pragma unroll
    for (int j = 0; j < 2; ++j) acc[i][j] = (f32x4){0.f, 0.f, 0.f, 0.f};

  for (int k0 = 0; k0 < KK; k0 += 32) {
    __syncthreads();
    {
      const int row = wave * 16 + srow;
      const long aoff = (long)(m0 + row) * KK + k0 + kc;
      const long boff = (long)(n0 + row) * KK + k0 + kc;
      async16(A_h + aoff, sAh + wave * 512);
      async16(B_h + boff, sBh + wave * 512);
      if (half == 0) {
        async16(ql + aoff, sAl + wave * 512);
        async16(kl_ + boff, sBl + wave * 512);
      }
    }
    __syncthreads();

    const int sw = (r16 >> 1) & 3;
    bfrag ah[2], bh[2], al[2], bl[2];
#pragma unroll
    for (int t2 = 0; t2 < 2; ++t2) {
      ah[t2] = *(const bfrag*)&sAh[(wm + t2 * 16 + r16) * 32 + (quad ^ sw) * 8];
      bh[t2] = *(const bfrag*)&sBh[(wn + t2 * 16 + r16) * 32 + (quad ^ sw) * 8];
      if (half == 0) {
        al[t2] = *(const bfrag*)&sAl[(wm + t2 * 16 + r16) * 32 + (quad ^ sw) * 8];
        bl[t2] = *(const bfrag*)&sBl[(wn + t2 * 16 + r16) * 32 + (quad ^ sw) * 8];
      }
    }
#pragma unroll
    for (int mt = 0; mt < 2; ++mt)
#pragma unroll
      for (int nt = 0; nt < 2; ++nt) {
        acc[mt][nt] = __builtin_amdgcn_mfma_f32_16x16x32_bf16(ah[mt], bh[nt], acc[mt][nt], 0, 0, 0);
        if (half == 0) {
          acc[mt][nt] = __builtin_amdgcn_mfma_f32_16x16x32_bf16(ah[mt], bl[nt], acc[mt][nt], 0, 0, 0);
          acc[mt][nt] = __builtin_amdgcn_mfma_f32_16x16x32_bf16(al[mt], bh[nt], acc[mt][nt], 0, 0, 0);
        }
      }
  }

#pragma unroll
  for (int mt = 0; mt < 2; ++mt)
#pragma unroll
    for (int nt = 0; nt < 2; ++nt)
#pragma unroll
      for (int reg = 0; reg < 4; ++reg) {
        const int ml = wm + mt * 16 + quad * 4 + reg;
        const int nl = wn + nt * 16 + r16;
        const float v = acc[mt][nt][reg];
        const long o = (long)(m0 + ml) * DD + n0 + nl;
        if (half == 0) {
          const ushort h = f2b(v);
          mqk_h[o] = h;
          mqk_l[o] = f2b(v - b2f(h));
        } else {
          mov_h[o] = f2b(v);
        }
      }
}

// ---------------------------------------------------------------------------
// bf16 MFMA GEMM, 128x128 block tile, 4 waves (2x2) of 64x64, R4 recipe
// schedule (dbuf 64KB -> 2 blocks/CU; STAGE(t+1) issued BEFORE compute; ONE
// vmcnt(0)+barrier per tile AFTER the MFMAs).
//
// R6 change: MFMA shape 16x16x32 -> 32x32x16 (m119: 2495 TF = 99.8% of
// dense peak vs 2075 for 16x16; the shape AITER/HK use). Same FLOPs ->
// HALF the MFMA instructions per tile (split 24, plain 16 per wave), same
// ds_read count; attacks the issue/dependency limit the R0-R5 nulls
// isolated (no pipe >30% busy at 76us across 6 schedule/occupancy variants).
//
// LDS layout & staging UNCHANGED from R4 (proven 0-conflict):
//   rows 128B = 8 chunks of 16B, phys chunk = logical ^ (row&7), realized
//   by pre-swizzling the per-lane GLOBAL source (LDS dest linear, m104).
//   SPLIT=1: BK=32, hi|lo packed per row (logical chunks 0-3 = hi k-chunks,
//     4-7 = lo). SPLIT=0: BK=64, chunks = k-chunks.
// 32x32x16 frag reads: lane reads row (lane&31), k = ks*16 + (lane>>5)*8
//   -> logical chunk = ks*2 + (lane>>5) [+4 for lo]; phys = c ^ (row&7).
//   8-lane groups read 8 consecutive rows at one logical chunk -> 8 distinct
//   phys chunks -> conflict-free (same invariant as R2-R5's measured 0).
// Fragment layouts (32x32x16, HW-verified C/D m74/m101):
//   A[m=lane&31][k=(lane>>5)*8+j], B[n=lane&31][k=(lane>>5)*8+j],
//   C/D: col=lane&31, row=(reg&3)+8*(reg>>2)+4*(lane>>5), reg in [0,16).
// TRIA : A staged from triangular tile layout; K limited to m0+128.
// SWIZ : XCD-locality block mapping (assumes xcd = blockIdx.x % 8):
//   1: 512 blocks, (b, m0)=P, n0: M=16 tiles, N=8 tiles
//   2: 544 blocks (logits tri), g=(blk&7)*68+(blk>>3); b=g/136, t=g%136
//   3: 512 blocks, causal-balanced: XCD x owns mtiles {x, 15-x}
//   4: 512 blocks, swapped roles (M=8 d-tiles, N=16 i-tiles)
// STORE 0: split bf16 (C0=hi, C1=lo); 1: tri fp32; 2: bf16; 3: fp32 + Res.
// ---------------------------------------------------------------------------
template <int SPLIT, int TRIA, int STORE, int SWIZ>
__global__ __launch_bounds__(256) void gemm_mfma(
    const ushort* __restrict__ Ah, const ushort* __restrict__ Al,
    const ushort* __restrict__ Bh, const ushort* __restrict__ Bl,
    void* __restrict__ C0, void* __restrict__ C1, const float* __restrict__ Res,
    int K, int lda, int ldb, int ldc,
    long bA, long bB, long bC, long bR) {
  extern __shared__ ushort smem[];   // 2 x 16384 ushorts (sA 8192 | sB 8192)

  int b, m0, n0, tiC = 0;
  if (SWIZ == 2) {
    const int g = (blockIdx.x & 7) * 68 + (blockIdx.x >> 3);
    b = g / NTRI;
    int t = g - b * NTRI;
    int ti = 0;
    while ((ti + 1) * (ti + 2) / 2 <= t) ++ti;
    const int tj = t - ti * (ti + 1) / 2;
    m0 = ti * 128; n0 = tj * 128; tiC = t;
  } else if (SWIZ == 1) {
    const int g = (blockIdx.x & 7) * 64 + (blockIdx.x >> 3);
    const int P = g >> 3;
    b = P >> 4;
    m0 = (P & 15) * 128;
    n0 = (g & 7) * 128;
  } else if (SWIZ == 3) {
    const int xcd = blockIdx.x & 7;
    const int idx = blockIdx.x >> 3;      // [0,64)
    const int q = idx >> 3;               // [0,8)
    b = q >> 1;
    const int mt_ = (q & 1) ? (15 - xcd) : xcd;
    m0 = mt_ * 128;
    n0 = (idx & 7) * 128;
  } else {  // SWIZ == 4
    const int g = (blockIdx.x & 7) * 64 + (blockIdx.x >> 3);
    const int P = g >> 3;
    b = P >> 4;
    n0 = (P & 15) * 128;
    m0 = (g & 7) * 128;
  }
  const int kmax = TRIA ? (m0 + 128) : K;
  int triA0 = 0;
  if (TRIA) { const int ti = m0 >> 7; triA0 = ti * (ti + 1) / 2; }

  const ushort* A_h = Ah + (long)b * bA;
  const ushort* B_h = Bh + (long)b * bB;
  const ushort* A_l = SPLIT ? Al + (long)b * bA : nullptr;
  const ushort* B_l = SPLIT ? Bl + (long)b * bB : nullptr;

  const int tid = threadIdx.x;
  const int lane = tid & 63, wave = tid >> 6;
  const int wm = (wave & 1) * 64, wn = (wave >> 1) * 64;
  const int l31 = lane & 31, khalf = lane >> 5;
  const int rs = l31 & 7;                      // row&7 swizzle key (frag reads)

  // staging lane mapping: 8 rows x 8 phys chunks per async16 (1KB)
  const int lrow = lane >> 3;                  // row within 8-row segment
  const int lc = (lane & 7) ^ lrow;            // logical chunk = phys ^ row&7
  // SPLIT: logical chunks 0-3 = hi k-chunks, 4-7 = lo k-chunks
  const int lckS = (lc & 3) * 8;
  const bool lo_src = lc >= 4;
  // plain: logical chunk = k-chunk of BK=64
  const int kcP = lc * 8;

  f32x16 acc[2][2];
#pragma unroll
  for (int i = 0; i < 2; ++i)
#pragma unroll
    for (int j = 0; j < 2; ++j)
#pragma unroll
      for (int r = 0; r < 16; ++r) acc[i][j][r] = 0.f;

  auto STAGE = [&](int db, int t) {
    ushort* dst = smem + db * 16384;
    if (SPLIT) {
      const int k0 = t << 5;
      const ushort* baseA = lo_src ? A_l : A_h;
      const ushort* baseB = lo_src ? B_l : B_h;
#pragma unroll
      for (int s = 0; s < 4; ++s) {
        const int seg = wave * 4 + s;          // [0,16): 8-row group
        const int row = seg * 8 + lrow;        // [0,128)
        async16(baseA + (long)(m0 + row) * lda + k0 + lckS, dst + seg * 512);
        async16(baseB + (long)(n0 + row) * ldb + k0 + lckS, dst + 8192 + seg * 512);
      }
    } else {
      const int k0 = t << 6;
#pragma unroll
      for (int s = 0; s < 4; ++s) {
        const int seg = wave * 4 + s;
        const int row = seg * 8 + lrow;
        long aoff;
        if (TRIA)
          aoff = (long)(triA0 + (k0 >> 7)) * TRI_ELEMS + (long)row * 128 + (k0 & 127) + kcP;
        else
          aoff = (long)(m0 + row) * lda + k0 + kcP;
        async16(A_h + aoff, dst + seg * 512);
        async16(B_h + (long)(n0 + row) * ldb + k0 + kcP, dst + 8192 + seg * 512);
      }
    }
  };

  const int T = kmax >> (SPLIT ? 5 : 6);
  STAGE(0, 0);
  asm volatile("s_waitcnt vmcnt(0)" ::: "memory");
  __builtin_amdgcn_s_barrier();
  __builtin_amdgcn_sched_barrier(0);

  for (int t = 0; t < T; ++t) {
    const int cur = t & 1;
    if (t + 1 < T) STAGE(cur ^ 1, t + 1);      // issue BEFORE compute
    const ushort* sA = smem + cur * 16384;
    const ushort* sB = sA + 8192;

    if (SPLIT) {
#pragma unroll
      for (int ks = 0; ks < 2; ++ks) {
        const int ch = ((ks * 2 + khalf) ^ rs) * 8;        // hi phys chunk
        const int cl = ((ks * 2 + khalf + 4) ^ rs) * 8;    // lo phys chunk
        bfrag ah[2], al[2], bh[2], bl[2];
#pragma unroll
        for (int mb = 0; mb < 2; ++mb) {
          const int arow = (wm + mb * 32 + l31) * 64;
          ah[mb] = *(const bfrag*)&sA[arow + ch];
          al[mb] = *(const bfrag*)&sA[arow + cl];
        }
#pragma unroll
        for (int nb = 0; nb < 2; ++nb) {
          const int brow = (wn + nb * 32 + l31) * 64;
          bh[nb] = *(const bfrag*)&sB[brow + ch];
          bl[nb] = *(const bfrag*)&sB[brow + cl];
        }
        __builtin_amdgcn_s_setprio(1);
#pragma unroll
        for (int mb = 0; mb < 2; ++mb)
#pragma unroll
          for (int nb = 0; nb < 2; ++nb) {
            acc[mb][nb] = __builtin_amdgcn_mfma_f32_32x32x16_bf16(ah[mb], bh[nb], acc[mb][nb], 0, 0, 0);
            acc[mb][nb] = __builtin_amdgcn_mfma_f32_32x32x16_bf16(ah[mb], bl[nb], acc[mb][nb], 0, 0, 0);
            acc[mb][nb] = __builtin_amdgcn_mfma_f32_32x32x16_bf16(al[mb], bh[nb], acc[mb][nb], 0, 0, 0);
          }
        __builtin_amdgcn_s_setprio(0);
      }
    } else {
#pragma unroll
      for (int ks = 0; ks < 4; ++ks) {
        const int ch = ((ks * 2 + khalf) ^ rs) * 8;        // phys chunk
        bfrag a2[2], b2[2];
#pragma unroll
        for (int mb = 0; mb < 2; ++mb)
          a2[mb] = *(const bfrag*)&sA[(wm + mb * 32 + l31) * 64 + ch];
#pragma unroll
        for (int nb = 0; nb < 2; ++nb)
          b2[nb] = *(const bfrag*)&sB[(wn + nb * 32 + l31) * 64 + ch];
        __builtin_amdgcn_s_setprio(1);
#pragma unroll
        for (int mb = 0; mb < 2; ++mb)
#pragma unroll
          for (int nb = 0; nb < 2; ++nb)
            acc[mb][nb] = __builtin_amdgcn_mfma_f32_32x32x16_bf16(a2[mb], b2[nb], acc[mb][nb], 0, 0, 0);
        __builtin_amdgcn_s_setprio(0);
      }
    }

    __builtin_amdgcn_sched_barrier(0);
    asm volatile("s_waitcnt vmcnt(0)" ::: "memory");   // t+1 loads landed
    __builtin_amdgcn_s_barrier();                      // buf[cur^1] ready
    __builtin_amdgcn_sched_barrier(0);
  }

  // epilogue: C/D col=lane&31, row=(reg&3)+8*(reg>>2)+4*khalf
#pragma unroll
  for (int mb = 0; mb < 2; ++mb)
#pragma unroll
    for (int nb = 0; nb < 2; ++nb)
#pragma unroll
      for (int reg = 0; reg < 16; ++reg) {
        const int ml = wm + mb * 32 + (reg & 3) + 8 * (reg >> 2) + 4 * khalf;
        const int nl = wn + nb * 32 + l31;
        const float v = acc[mb][nb][reg];
        if (STORE == 0) {
          ushort* Ch = (ushort*)C0 + (long)b * bC;
          ushort* Cl = (ushort*)C1 + (long)b * bC;
          const long o = (long)(m0 + ml) * ldc + n0 + nl;
          const ushort h = f2b(v);
          Ch[o] = h;
          Cl[o] = f2b(v - b2f(h));
        } else if (STORE == 1) {
          float* C = (float*)C0 + (long)b * bC + (long)tiC * TRI_ELEMS;
          C[ml * 128 + nl] = v;
        } else if (STORE == 2) {
          ushort* C = (ushort*)C0 + (long)b * bC;
          C[(long)(m0 + ml) * ldc + n0 + nl] = f2b(v);
        } else {
          float* C = (float*)C0 + (long)b * bC;
          const float* R = Res + (long)b * bR;
          const long o = (long)(m0 + ml) * ldc + n0 + nl;
          C[o] = R[o] + v;
        }
      }
}

// ---------------------------------------------------------------------------
// Causal softmax over triangular-tiled logits. One block per row (b, i).
// Writes bf16 A in tri layout, zero-filling diagonal-tile cols beyond i.
// ---------------------------------------------------------------------------
__global__ __launch_bounds__(256) void softmax_tri(
    const float* __restrict__ L, ushort* __restrict__ Aout) {
  const int row = blockIdx.x;
  const int b = row >> 11, i = row & (NN - 1);
  const int ti = i >> 7, ml = i & 127;
  const long base = (long)b * ((long)NTRI * TRI_ELEMS);
  const int trib = ti * (ti + 1) / 2;
  const int len = i + 1;
  const int tot = (ti + 1) * 128;
  const int tid = threadIdx.x;
  __shared__ float red[256];
  float vv[8];
  float m = -INFINITY;
#pragma unroll
  for (int u = 0; u < 8; ++u) {
    const int j = tid + u * 256;
    if (j < len) {
      const float v = L[base + (long)(trib + (j >> 7)) * TRI_ELEMS + ml * 128 + (j & 127)];
      vv[u] = v;
      m = fmaxf(m, v);
    }
  }
  red[tid] = m; __syncthreads();
  for (int s = 128; s; s >>= 1) { if (tid < s) red[tid] = fmaxf(red[tid], red[tid + s]); __syncthreads(); }
  m = red[0]; __syncthreads();
  float sum = 0.f;
#pragma unroll
  for (int u = 0; u < 8; ++u) {
    const int j = tid + u * 256;
    if (j < len) { const float e = __expf(vv[u] - m); vv[u] = e; sum += e; }
  }
  red[tid] = sum; __syncthreads();
  for (int s = 128; s; s >>= 1) { if (tid < s) red[tid] += red[tid + s]; __syncthreads(); }
  const float inv = 1.f / red[0];
#pragma unroll
  for (int u = 0; u < 8; ++u) {
    const int j = tid + u * 256;
    if (j < tot) {
      const ushort o = (j < len) ? f2b(vv[u] * inv) : (ushort)0;
      Aout[base + (long)(trib + (j >> 7)) * TRI_ELEMS + ml * 128 + (j & 127)] = o;
    }
  }
}

// ---------------------------------------------------------------------------
// Pipeline (all MFMA operands k-contiguous by construction):
//  0. prep: x -> x_hi, xT hi/lo; W_Q..W_O -> WT [d][k] bf16     (1 dispatch)
//  1. gemm_w: Mqk (split) + Mov (plain) in one 512-block dispatch
//  2. tT[i,d] = sum_e xT[i,e] Mqk[d,e]      split, SWIZ=1, 512 blocks
//  3. logits[i,j] = sum_d xT[i,d] tT[j,d]   split, tri tiles, SWIZ=2, 544
//  4. A = causal softmax (bf16, tri layout, zero-padded diag tiles)
//  5. ctxT[i,e] = sum_{t<=i} A[i,t] x[e,t]  plain, causal K, SWIZ=3 (bal)
//  6. out[d,i] = x[d,i] + sum_e Mov[d,e] ctxT[i,e]   plain + res, SWIZ=4
// ---------------------------------------------------------------------------
extern "C" void kernel_launch(void* const* d_in, const int* in_sizes, int n_in,
                              void* d_out, int out_size, void* d_ws, size_t ws_size,
                              hipStream_t stream) {
  const float* x = (const float*)d_in[0];
  const float* WQ = (const float*)d_in[1];
  const float* WK = (const float*)d_in[2];
  const float* WV = (const float*)d_in[3];
  const float* WO = (const float*)d_in[4];
  float* out = (float*)d_out;

  const long XE = (long)BB * DD * NN;    // 8M elements
  const long WE = (long)DD * KK;         // 1M elements
  ushort* x_hi = (ushort*)d_ws;
  ushort* xTh = x_hi + XE;
  ushort* xTl = xTh + XE;
  ushort* wqT_h = xTl + XE;
  ushort* wqT_l = wqT_h + WE;
  ushort* wkT_h = wqT_l + WE;
  ushort* wkT_l = wkT_h + WE;
  ushort* wvT_h = wkT_l + WE;
  ushort* woT_h = wvT_h + WE;
  ushort* mqk_h = woT_h + WE;
  ushort* mqk_l = mqk_h + WE;
  ushort* mov_h = mqk_l + WE;
  ushort* tTh = mov_h + WE;
  ushort* tTl = tTh + XE;
  float* logits = (float*)(tTl + XE);    // B*NTRI*TRI_ELEMS fp32 (~35.7MB)
  ushort* A_tri = tTh;                   // overlays tT hi+lo (dead after step 3)
  ushort* ctxT = (ushort*)logits;        // overlays logits (dead after softmax)
  const long TRIB = (long)NTRI * TRI_ELEMS;
  const long XB = XE / BB;

  prep<<<dim3(64, 32, 6), dim3(32, 8), 0, stream>>>(
      x, WQ, WK, WV, WO, x_hi, xTh, xTl,
      wqT_h, wqT_l, wkT_h, wkT_l, wvT_h, woT_h);

  // Mqk (split) + Mov (plain), merged 64-tile dispatch
  gemm_w<<<dim3(512), 256, 16384, stream>>>(
      wqT_h, wqT_l, wkT_h, wkT_l, wvT_h, woT_h, mqk_h, mqk_l, mov_h);

  // tT = xT * Mqk^T (split, 32x32x16, recipe dbuf BK=32, 64KB, 2 blk/CU)
  gemm_mfma<1, 0, 0, 1><<<dim3(512), 256, 65536, stream>>>(
      xTh, xTl, mqk_h, mqk_l, tTh, tTl, nullptr,
      DD, DD, DD, DD, XB, 0, XB, 0);

  // logits (lower tri tiles, split 32x32x16 recipe dbuf)
  gemm_mfma<1, 0, 1, 2><<<dim3(BB * NTRI), 256, 65536, stream>>>(
      xTh, xTl, tTh, tTl, logits, nullptr, nullptr,
      DD, DD, DD, 0, XB, XB, TRIB, 0);

  softmax_tri<<<dim3(BB * NN), 256, 0, stream>>>(logits, A_tri);

  // ctxT = A * x^T (tri A, causal K-limit, balanced XCD swizzle, dbuf)
  gemm_mfma<0, 1, 2, 3><<<dim3(512), 256, 65536, stream>>>(
      A_tri, nullptr, x_hi, nullptr, ctxT, nullptr, nullptr,
      NN, 0, NN, DD, TRIB, XB, XB, 0);

  // out = x + Mov * ctx (SWIZ=4: M=8 d-tiles, N=16 i-tiles, dbuf)
  gemm_mfma<0, 0, 3, 4><<<dim3(512), 256, 65536, stream>>>(
      mov_h, nullptr, ctxT, nullptr, out, nullptr, x,
      DD, DD, DD, NN, 0, XB, XB, XB);
}

// Round 7
// 339.412 us; speedup vs baseline: 1.0279x; 1.0150x over previous
//
#include <hip/hip_runtime.h>
#include <hip/hip_bf16.h>
#include <math.h>

// Problem constants: B=4, D=1024, N=2048, K=1024, fp32 in/out.
#define BB 4
#define DD 1024
#define NN 2048
#define KK 1024
#define NT128 16            // NN/128
#define NTRI 136            // 16*17/2 lower-triangular 128x128 tiles
#define TRI_ELEMS 16384     // 128*128

typedef __attribute__((ext_vector_type(4))) float f32x4;
typedef __attribute__((ext_vector_type(8))) short bfrag;

typedef __attribute__((address_space(1))) const unsigned int gu32;
typedef __attribute__((address_space(3))) unsigned int lu32;

// async global->LDS, 16B per lane; LDS dest = base + lane*16 (wave-uniform base)
__device__ __forceinline__ void async16(const void* g, void* l) {
  __builtin_amdgcn_global_load_lds((gu32*)g, (lu32*)l, 16, 0, 0);
}

__device__ __forceinline__ ushort f2b(float f) {  // fp32 -> bf16 RNE
  union { float f; unsigned u; } c; c.f = f;
  unsigned u = c.u + 0x7fffu + ((c.u >> 16) & 1u);
  return (ushort)(u >> 16);
}
__device__ __forceinline__ float b2f(ushort h) {
  union { unsigned u; float f; } c; c.u = ((unsigned)h) << 16;
  return c.f;
}

// ---------------------------------------------------------------------------
// prep: merged input transform, grid (64, 32, 6), block (32,8).
//  z<4 : x [b=z][d][n] fp32 -> x_hi (bf16 same layout), xT hi/lo ([b][n][d])
//  z>=4: weight w = (z-4)*2 + (bx>>5): W (K x D, [k][d]) -> WT [d][k] bf16
//        (WQ, WK split hi+lo; WV, WO hi only)
// ---------------------------------------------------------------------------
__global__ __launch_bounds__(256) void prep(
    const float* __restrict__ x,
    const float* __restrict__ WQ, const float* __restrict__ WK,
    const float* __restrict__ WV, const float* __restrict__ WO,
    ushort* __restrict__ xhi, ushort* __restrict__ xTh, ushort* __restrict__ xTl,
    ushort* __restrict__ qh, ushort* __restrict__ ql,
    ushort* __restrict__ kh, ushort* __restrict__ kl_,
    ushort* __restrict__ vh, ushort* __restrict__ oh) {
  const int z = blockIdx.z;
  const int tx = threadIdx.x, ty = threadIdx.y;
  __shared__ float tile[32][33];
  if (z < 4) {
    const int b = z;
    const int n0 = blockIdx.x * 32, d0 = blockIdx.y * 32;
    const float* xb = x + (long)b * DD * NN;
    ushort* xhb = xhi + (long)b * DD * NN;
#pragma unroll
    for (int r = 0; r < 4; ++r) {
      const int dl = ty + r * 8;
      const float v = xb[(long)(d0 + dl) * NN + n0 + tx];
      tile[dl][tx] = v;
      xhb[(long)(d0 + dl) * NN + n0 + tx] = f2b(v);
    }
    __syncthreads();
#pragma unroll
    for (int r = 0; r < 4; ++r) {
      const int nl = ty + r * 8;
      const float v = tile[tx][nl];
      const ushort h = f2b(v);
      const long o = (long)b * NN * DD + (long)(n0 + nl) * DD + d0 + tx;
      xTh[o] = h;
      xTl[o] = f2b(v - b2f(h));
    }
  } else {
    const int w = (z - 4) * 2 + (blockIdx.x >> 5);
    const float* W = (w == 0) ? WQ : (w == 1) ? WK : (w == 2) ? WV : WO;
    ushort* Th = (w == 0) ? qh : (w == 1) ? kh : (w == 2) ? vh : oh;
    ushort* Tl = (w == 0) ? ql : (w == 1) ? kl_ : nullptr;
    const int k0 = (blockIdx.x & 31) * 32, d0 = blockIdx.y * 32;
#pragma unroll
    for (int r = 0; r < 4; ++r) {
      const int kl = ty + r * 8;
      tile[kl][tx] = W[(long)(k0 + kl) * DD + d0 + tx];
    }
    __syncthreads();
#pragma unroll
    for (int r = 0; r < 4; ++r) {
      const int dl = ty + r * 8;
      const float v = tile[tx][dl];              // = W[k0+tx][d0+dl]
      const ushort h = f2b(v);
      const long o = (long)(d0 + dl) * KK + k0 + tx;
      Th[o] = h;
      if (Tl) Tl[o] = f2b(v - b2f(h));
    }
  }
}

// ---------------------------------------------------------------------------
// Merged weight-product GEMM, 64x64 tiles, BK=32, 512 blocks:
//   id<256 : Mqk[m,n] = sum_k wqT[m,k] wkT[n,k]  (split 3-MFMA, split store)
//   id>=256: Mov[m,n] = sum_k woT[m,k] wvT[n,k]  (plain bf16)
// ---------------------------------------------------------------------------
__global__ __launch_bounds__(256) void gemm_w(
    const ushort* __restrict__ qh, const ushort* __restrict__ ql,
    const ushort* __restrict__ kh, const ushort* __restrict__ kl_,
    const ushort* __restrict__ vh, const ushort* __restrict__ oh,
    ushort* __restrict__ mqk_h, ushort* __restrict__ mqk_l,
    ushort* __restrict__ mov_h) {
  extern __shared__ ushort smem[];
  ushort* sAh = smem;            // [64][32] 4KB
  ushort* sAl = smem + 2048;
  ushort* sBh = smem + 4096;
  ushort* sBl = smem + 6144;

  const int id = blockIdx.x;
  const int half = id >> 8;                  // 0 = Mqk (split), 1 = Mov (plain)
  const int t = id & 255;
  const int m0 = (t >> 4) * 64, n0 = (t & 15) * 64;
  const ushort* A_h = half ? oh : qh;
  const ushort* B_h = half ? vh : kh;

  const int tid = threadIdx.x;
  const int lane = tid & 63, wave = tid >> 6;
  const int wm = (wave & 1) * 32, wn = (wave >> 1) * 32;
  const int r16 = lane & 15, quad = lane >> 4;
  const int kc = ((lane & 3) ^ ((lane >> 3) & 3)) * 8;   // swizzled k-chunk
  const int srow = lane >> 2;

  f32x4 acc[2][2];
#pragma unroll
  for (int i = 0; i < 2; ++i)
#pragma unroll
    for (int j = 0; j < 2; ++j) acc[i][j] = (f32x4){0.f, 0.f, 0.f, 0.f};

  for (int k0 = 0; k0 < KK; k0 += 32) {
    __syncthreads();
    {
      const int row = wave * 16 + srow;
      const long aoff = (long)(m0 + row) * KK + k0 + kc;
      const long boff = (long)(n0 + row) * KK + k0 + kc;
      async16(A_h + aoff, sAh + wave * 512);
      async16(B_h + boff, sBh + wave * 512);
      if (half == 0) {
        async16(ql + aoff, sAl + wave * 512);
        async16(kl_ + boff, sBl + wave * 512);
      }
    }
    __syncthreads();

    const int sw = (r16 >> 1) & 3;
    bfrag ah[2], bh[2], al[2], bl[2];
#pragma unroll
    for (int t2 = 0; t2 < 2; ++t2) {
      ah[t2] = *(const bfrag*)&sAh[(wm + t2 * 16 + r16) * 32 + (quad ^ sw) * 8];
      bh[t2] = *(const bfrag*)&sBh[(wn + t2 * 16 + r16) * 32 + (quad ^ sw) * 8];
      if (half == 0) {
        al[t2] = *(const bfrag*)&sAl[(wm + t2 * 16 + r16) * 32 + (quad ^ sw) * 8];
        bl[t2] = *(const bfrag*)&sBl[(wn + t2 * 16 + r16) * 32 + (quad ^ sw) * 8];
      }
    }
#pragma unroll
    for (int mt = 0; mt < 2; ++mt)
#pragma unroll
      for (int nt = 0; nt < 2; ++nt) {
        acc[mt][nt] = __builtin_amdgcn_mfma_f32_16x16x32_bf16(ah[mt], bh[nt], acc[mt][nt], 0, 0, 0);
        if (half == 0) {
          acc[mt][nt] = __builtin_amdgcn_mfma_f32_16x16x32_bf16(ah[mt], bl[nt], acc[mt][nt], 0, 0, 0);
          acc[mt][nt] = __builtin_amdgcn_mfma_f32_16x16x32_bf16(al[mt], bh[nt], acc[mt][nt], 0, 0, 0);
        }
      }
  }

#pragma unroll
  for (int mt = 0; mt < 2; ++mt)
#pragma unroll
    for (int nt = 0; nt < 2; ++nt)
#pragma unroll
      for (int reg = 0; reg < 4; ++reg) {
        const int ml = wm + mt * 16 + quad * 4 + reg;
        const int nl = wn + nt * 16 + r16;
        const float v = acc[mt][nt][reg];
        const long o = (long)(m0 + ml) * DD + n0 + nl;
        if (half == 0) {
          const ushort h = f2b(v);
          mqk_h[o] = h;
          mqk_l[o] = f2b(v - b2f(h));
        } else {
          mov_h[o] = f2b(v);
        }
      }
}

// ---------------------------------------------------------------------------
// gemm8: the two big split GEMMs as PLAIN bf16 GEMMs over K=3072 via the
// split-as-K identity  C = [Ah|Al|Ah] . [Bh|Bh|Bl]^T  (= hh + lh + hl),
// in the m201-verified 8-phase regime (the measured gate for T3/T4/T5):
//   256x128 tile, BK=64, 8 waves (512 thr) as 4Mx2N -> per-wave 64x64.
//   3 staging buffers, static 144KB LDS (R3-proven size), 1 block/CU.
//   Per K-tile t (buf = t%3): ONE counted-vmcnt wait + 2 barriers:
//     vmcnt(6)            ; drains tile t's 6 loads (issued 2 tiles ago ->
//                         ; a full K-tile of slack); t+1's 6 stay in flight
//     s_barrier           ; B1: buf[t%3] resident block-wide
//     phase a: 8 ds_read(ksub0) | STAGE half-0 of t+2 | lgkmcnt(0)
//              setprio(1) 16 MFMA setprio(0)
//     s_barrier           ; B2: phase lock (wave role-split -> T5 pays)
//     phase b: 8 ds_read(ksub1) | STAGE half-1 of t+2 | lgkmcnt(0)
//              setprio(1) 16 MFMA setprio(0)
//   Buffer safety: STAGE targets buf[(t+2)%3] = buf[(t-1)%3]; every wave's
//   t-1 ds_reads were register-consumed (lgkmcnt(0)) before it crossed B1.
//   vmcnt safety: the wait precedes B1, so after B1 ALL waves' tile-t loads
//   have landed.
// LDS layout: A [256][64] 32KB + B [128][64] 16KB per buffer; rows 128B = 8
//   chunks of 16B; phys chunk = logical ^ (row&7), realized by pre-swizzling
//   the per-lane GLOBAL source (LDS dest linear, m104/m173). Frag-read
//   pattern byte-identical to R4-plain (measured 0 conflicts).
// Source select: third = t>>4: A = {Ah,Al,Ah}[third], B = {Bh,Bh,Bl}[third],
//   k0 = (t&15)*64.
// MODE 0: step 2 (tT), 256 blocks, split hi/lo bf16 store.
// MODE 1: step 3 (logits), 288 blocks, fp32 tri store; block = 2 tri-rows
//   (ti = 2I, 2I+1), cols beyond diag (jt > ti) discarded.
// ---------------------------------------------------------------------------
template <int MODE>
__global__ __launch_bounds__(512) void gemm8(
    const ushort* __restrict__ Ah, const ushort* __restrict__ Al,
    const ushort* __restrict__ Bh, const ushort* __restrict__ Bl,
    void* __restrict__ C0, void* __restrict__ C1,
    int lda, int ldb, int ldc, long bA, long bB, long bC) {
  __shared__ ushort smem[73728];               // 3 x 24576 ushorts = 144KB

  int b, m0, n0, jt = 0;
  if (MODE == 0) {
    const int g = (blockIdx.x & 7) * 32 + (blockIdx.x >> 3);  // [0,256)
    const int mt = g >> 3;                    // [0,32)
    b = mt >> 3;
    m0 = (mt & 7) * 256;
    n0 = (g & 7) * 128;
  } else {
    const int g = (blockIdx.x & 7) * 36 + (blockIdx.x >> 3);  // [0,288)
    b = g / 72;
    const int r = g - b * 72;
    int I = 0;
    while ((I + 1) * (I + 2) <= r) ++I;       // prefix(I) = I*(I+1)
    jt = r - I * (I + 1);                     // jt <= 2I+1
    m0 = I * 256;
    n0 = jt * 128;
  }

  const ushort* A_hb = Ah + (long)b * bA;
  const ushort* A_lb = Al + (long)b * bA;
  const ushort* B_hb = Bh + (long)b * bB;
  const ushort* B_lb = Bl + (long)b * bB;

  const int tid = threadIdx.x;
  const int lane = tid & 63, wave = tid >> 6;  // wave in [0,8)
  const int wm = (wave & 3) * 64, wn = (wave >> 2) * 64;
  const int r16 = lane & 15, quad = lane >> 4;
  const int rk = r16 & 7;

  // staging lane mapping: 8 rows x 8 phys chunks per async16 (1KB)
  const int lrow = lane >> 3;                  // row within 8-row segment
  const int lc = (lane & 7) ^ lrow;            // logical chunk = phys ^ row&7
  const int kc = lc * 8;                       // k-offset within BK=64 row

  f32x4 acc[4][4];
#pragma unroll
  for (int i = 0; i < 4; ++i)
#pragma unroll
    for (int j = 0; j < 4; ++j) acc[i][j] = (f32x4){0.f, 0.f, 0.f, 0.f};

  // stage half h of K-tile t into buffer db (3 async16/lane)
  auto STAGE = [&](int db, int t, int h) {
    const int third = t >> 4;
    const int k0 = (t & 15) << 6;
    const ushort* A = (third == 1) ? A_lb : A_hb;
    const ushort* B = (third == 2) ? B_lb : B_hb;
    ushort* dst = smem + db * 24576;
#pragma unroll
    for (int s = 0; s < 2; ++s) {              // A: 32 segs, 4/wave, 2/half
      const int seg = wave * 4 + h * 2 + s;    // [0,32)
      const int row = seg * 8 + lrow;          // [0,256)
      async16(A + (long)(m0 + row) * lda + k0 + kc, dst + seg * 512);
    }
    {                                          // B: 16 segs, 2/wave, 1/half
      const int seg = wave * 2 + h;            // [0,16)
      const int row = seg * 8 + lrow;          // [0,128)
      async16(B + (long)(n0 + row) * ldb + k0 + kc, dst + 16384 + seg * 512);
    }
  };

  const int T = 48;                            // 3 * KK/64 (split-as-K)
  STAGE(0, 0, 0); STAGE(0, 0, 1);              // prologue: 2 tiles in flight
  STAGE(1, 1, 0); STAGE(1, 1, 1);

  for (int t = 0; t < T; ++t) {
    const int cur = t % 3;
    if (t + 1 < T) asm volatile("s_waitcnt vmcnt(6)" ::: "memory");
    else           asm volatile("s_waitcnt vmcnt(0)" ::: "memory");
    __builtin_amdgcn_s_barrier();              // B1: buf[cur] ready
    __builtin_amdgcn_sched_barrier(0);

    const ushort* sA = smem + cur * 24576;
    const ushort* sB = sA + 16384;
#pragma unroll
    for (int ks = 0; ks < 2; ++ks) {
      const int ch = ((ks * 4 + quad) ^ rk) * 8;         // physical chunk
      bfrag a4[4], b4[4];
#pragma unroll
      for (int f = 0; f < 4; ++f) {
        a4[f] = *(const bfrag*)&sA[(wm + f * 16 + r16) * 64 + ch];
        b4[f] = *(const bfrag*)&sB[(wn + f * 16 + r16) * 64 + ch];
      }
      if (t + 2 < T) STAGE((t + 2) % 3, t + 2, ks);      // overlap w/ reads
      asm volatile("s_waitcnt lgkmcnt(0)" ::: "memory");
      __builtin_amdgcn_sched_barrier(0);                 // rule 18 fence
      __builtin_amdgcn_s_setprio(1);
#pragma unroll
      for (int mt = 0; mt < 4; ++mt)
#pragma unroll
        for (int nt = 0; nt < 4; ++nt)
          acc[mt][nt] = __builtin_amdgcn_mfma_f32_16x16x32_bf16(a4[mt], b4[nt], acc[mt][nt], 0, 0, 0);
      __builtin_amdgcn_s_setprio(0);
      if (ks == 0) __builtin_amdgcn_s_barrier();         // B2: phase lock
    }
  }

  // epilogue: C/D col=lane&15 (r16), row=quad*4+reg (m89)
#pragma unroll
  for (int mt = 0; mt < 4; ++mt)
#pragma unroll
    for (int nt = 0; nt < 4; ++nt)
#pragma unroll
      for (int reg = 0; reg < 4; ++reg) {
        const int ml = wm + mt * 16 + quad * 4 + reg;    // [0,256)
        const int nl = wn + nt * 16 + r16;               // [0,128)
        const float v = acc[mt][nt][reg];
        if (MODE == 0) {
          ushort* Ch = (ushort*)C0 + (long)b * bC;
          ushort* Cl = (ushort*)C1 + (long)b * bC;
          const long o = (long)(m0 + ml) * ldc + n0 + nl;
          const ushort h = f2b(v);
          Ch[o] = h;
          Cl[o] = f2b(v - b2f(h));
        } else {
          const int gi = m0 + ml;                        // row in batch
          const int ti = gi >> 7;
          if (jt <= ti) {
            float* C = (float*)C0 + (long)b * bC;
            C[(long)(ti * (ti + 1) / 2 + jt) * TRI_ELEMS + (gi & 127) * 128 + nl] = v;
          }
        }
      }
}

// ---------------------------------------------------------------------------
// bf16 MFMA GEMM (R4 version, best measured for steps 5/6): 128x128 tile,
// 4 waves (2x2) of 64x64, BK=64, recipe dbuf schedule (STAGE before compute,
// one vmcnt(0)+barrier per tile after MFMAs), ^(row&7) swizzle (0 conflicts).
// TRIA : A staged from triangular tile layout; K limited to m0+128.
// SWIZ 3: causal-balanced XCD map;  SWIZ 4: swapped-role XCD map.
// STORE 2: bf16 row-major;  STORE 3: fp32 row-major + residual from Res.
// ---------------------------------------------------------------------------
template <int TRIA, int STORE, int SWIZ>
__global__ __launch_bounds__(256) void gemm_mfma(
    const ushort* __restrict__ Ah, const ushort* __restrict__ Bh,
    void* __restrict__ C0, const float* __restrict__ Res,
    int K, int lda, int ldb, int ldc,
    long bA, long bB, long bC, long bR) {
  extern __shared__ ushort smem[];   // 2 x 16384 ushorts (sA 8192 | sB 8192)

  int b, m0, n0;
  if (SWIZ == 3) {
    const int xcd = blockIdx.x & 7;
    const int idx = blockIdx.x >> 3;      // [0,64)
    const int q = idx >> 3;               // [0,8)
    b = q >> 1;
    const int mt_ = (q & 1) ? (15 - xcd) : xcd;
    m0 = mt_ * 128;
    n0 = (idx & 7) * 128;
  } else {  // SWIZ == 4
    const int g = (blockIdx.x & 7) * 64 + (blockIdx.x >> 3);
    const int P = g >> 3;
    b = P >> 4;
    n0 = (P & 15) * 128;
    m0 = (g & 7) * 128;
  }
  const int kmax = TRIA ? (m0 + 128) : K;
  int triA0 = 0;
  if (TRIA) { const int ti = m0 >> 7; triA0 = ti * (ti + 1) / 2; }

  const ushort* A_h = Ah + (long)b * bA;
  const ushort* B_h = Bh + (long)b * bB;

  const int tid = threadIdx.x;
  const int lane = tid & 63, wave = tid >> 6;
  const int wm = (wave & 1) * 64, wn = (wave >> 1) * 64;
  const int r16 = lane & 15, quad = lane >> 4;
  const int rk = r16 & 7;

  const int lrow = lane >> 3;
  const int lc = (lane & 7) ^ lrow;
  const int kcP = lc * 8;

  f32x4 acc[4][4];
#pragma unroll
  for (int i = 0; i < 4; ++i)
#pragma unroll
    for (int j = 0; j < 4; ++j) acc[i][j] = (f32x4){0.f, 0.f, 0.f, 0.f};

  auto STAGE = [&](int db, int t) {
    ushort* dst = smem + db * 16384;
    const int k0 = t << 6;
#pragma unroll
    for (int s = 0; s < 4; ++s) {
      const int seg = wave * 4 + s;
      const int row = seg * 8 + lrow;
      long aoff;
      if (TRIA)
        aoff = (long)(triA0 + (k0 >> 7)) * TRI_ELEMS + (long)row * 128 + (k0 & 127) + kcP;
      else
        aoff = (long)(m0 + row) * lda + k0 + kcP;
      async16(A_h + aoff, dst + seg * 512);
      async16(B_h + (long)(n0 + row) * ldb + k0 + kcP, dst + 8192 + seg * 512);
    }
  };

  const int T = kmax >> 6;
  STAGE(0, 0);
  asm volatile("s_waitcnt vmcnt(0)" ::: "memory");
  __builtin_amdgcn_s_barrier();
  __builtin_amdgcn_sched_barrier(0);

  for (int t = 0; t < T; ++t) {
    const int cur = t & 1;
    if (t + 1 < T) STAGE(cur ^ 1, t + 1);      // issue BEFORE compute
    const ushort* sA = smem + cur * 16384;
    const ushort* sB = sA + 8192;

#pragma unroll
    for (int ksub = 0; ksub < 2; ++ksub) {
      const int ch = ((ksub * 4 + quad) ^ rk) * 8;     // physical chunk
      bfrag a4[4], b4[4];
#pragma unroll
      for (int f = 0; f < 4; ++f) {
        a4[f] = *(const bfrag*)&sA[(wm + f * 16 + r16) * 64 + ch];
        b4[f] = *(const bfrag*)&sB[(wn + f * 16 + r16) * 64 + ch];
      }
      __builtin_amdgcn_s_setprio(1);
#pragma unroll
      for (int mt = 0; mt < 4; ++mt)
#pragma unroll
        for (int nt = 0; nt < 4; ++nt)
          acc[mt][nt] = __builtin_amdgcn_mfma_f32_16x16x32_bf16(a4[mt], b4[nt], acc[mt][nt], 0, 0, 0);
      __builtin_amdgcn_s_setprio(0);
    }

    __builtin_amdgcn_sched_barrier(0);
    asm volatile("s_waitcnt vmcnt(0)" ::: "memory");   // t+1 loads landed
    __builtin_amdgcn_s_barrier();                      // buf[cur^1] ready
    __builtin_amdgcn_sched_barrier(0);
  }

  // epilogue
#pragma unroll
  for (int mt = 0; mt < 4; ++mt)
#pragma unroll
    for (int nt = 0; nt < 4; ++nt)
#pragma unroll
      for (int reg = 0; reg < 4; ++reg) {
        const int ml = wm + mt * 16 + quad * 4 + reg;
        const int nl = wn + nt * 16 + r16;
        const float v = acc[mt][nt][reg];
        if (STORE == 2) {
          ushort* C = (ushort*)C0 + (long)b * bC;
          C[(long)(m0 + ml) * ldc + n0 + nl] = f2b(v);
        } else {
          float* C = (float*)C0 + (long)b * bC;
          const float* R = Res + (long)b * bR;
          const long o = (long)(m0 + ml) * ldc + n0 + nl;
          C[o] = R[o] + v;
        }
      }
}

// ---------------------------------------------------------------------------
// Causal softmax over triangular-tiled logits. One block per row (b, i).
// Writes bf16 A in tri layout, zero-filling diagonal-tile cols beyond i.
// ---------------------------------------------------------------------------
__global__ __launch_bounds__(256) void softmax_tri(
    const float* __restrict__ L, ushort* __restrict__ Aout) {
  const int row = blockIdx.x;
  const int b = row >> 11, i = row & (NN - 1);
  const int ti = i >> 7, ml = i & 127;
  const long base = (long)b * ((long)NTRI * TRI_ELEMS);
  const int trib = ti * (ti + 1) / 2;
  const int len = i + 1;
  const int tot = (ti + 1) * 128;
  const int tid = threadIdx.x;
  __shared__ float red[256];
  float vv[8];
  float m = -INFINITY;
#pragma unroll
  for (int u = 0; u < 8; ++u) {
    const int j = tid + u * 256;
    if (j < len) {
      const float v = L[base + (long)(trib + (j >> 7)) * TRI_ELEMS + ml * 128 + (j & 127)];
      vv[u] = v;
      m = fmaxf(m, v);
    }
  }
  red[tid] = m; __syncthreads();
  for (int s = 128; s; s >>= 1) { if (tid < s) red[tid] = fmaxf(red[tid], red[tid + s]); __syncthreads(); }
  m = red[0]; __syncthreads();
  float sum = 0.f;
#pragma unroll
  for (int u = 0; u < 8; ++u) {
    const int j = tid + u * 256;
    if (j < len) { const float e = __expf(vv[u] - m); vv[u] = e; sum += e; }
  }
  red[tid] = sum; __syncthreads();
  for (int s = 128; s; s >>= 1) { if (tid < s) red[tid] += red[tid + s]; __syncthreads(); }
  const float inv = 1.f / red[0];
#pragma unroll
  for (int u = 0; u < 8; ++u) {
    const int j = tid + u * 256;
    if (j < tot) {
      const ushort o = (j < len) ? f2b(vv[u] * inv) : (ushort)0;
      Aout[base + (long)(trib + (j >> 7)) * TRI_ELEMS + ml * 128 + (j & 127)] = o;
    }
  }
}

// ---------------------------------------------------------------------------
// Pipeline (all MFMA operands k-contiguous by construction):
//  0. prep: x -> x_hi, xT hi/lo; W_Q..W_O -> WT [d][k] bf16     (1 dispatch)
//  1. gemm_w: Mqk (split) + Mov (plain) in one 512-block dispatch
//  2. tT[i,d] = sum_e xT[i,e] Mqk[d,e]      gemm8<0>, 256 blocks, K=3072
//  3. logits[i,j] = sum_d xT[i,d] tT[j,d]   gemm8<1>, 288 blocks (tri)
//  4. A = causal softmax (bf16, tri layout, zero-padded diag tiles)
//  5. ctxT[i,e] = sum_{t<=i} A[i,t] x[e,t]  plain, causal K, SWIZ=3 (bal)
//  6. out[d,i] = x[d,i] + sum_e Mov[d,e] ctxT[i,e]   plain + res, SWIZ=4
// ---------------------------------------------------------------------------
extern "C" void kernel_launch(void* const* d_in, const int* in_sizes, int n_in,
                              void* d_out, int out_size, void* d_ws, size_t ws_size,
                              hipStream_t stream) {
  const float* x = (const float*)d_in[0];
  const float* WQ = (const float*)d_in[1];
  const float* WK = (const float*)d_in[2];
  const float* WV = (const float*)d_in[3];
  const float* WO = (const float*)d_in[4];
  float* out = (float*)d_out;

  const long XE = (long)BB * DD * NN;    // 8M elements
  const long WE = (long)DD * KK;         // 1M elements
  ushort* x_hi = (ushort*)d_ws;
  ushort* xTh = x_hi + XE;
  ushort* xTl = xTh + XE;
  ushort* wqT_h = xTl + XE;
  ushort* wqT_l = wqT_h + WE;
  ushort* wkT_h = wqT_l + WE;
  ushort* wkT_l = wkT_h + WE;
  ushort* wvT_h = wkT_l + WE;
  ushort* woT_h = wvT_h + WE;
  ushort* mqk_h = woT_h + WE;
  ushort* mqk_l = mqk_h + WE;
  ushort* mov_h = mqk_l + WE;
  ushort* tTh = mov_h + WE;
  ushort* tTl = tTh + XE;
  float* logits = (float*)(tTl + XE);    // B*NTRI*TRI_ELEMS fp32 (~35.7MB)
  ushort* A_tri = tTh;                   // overlays tT hi+lo (dead after step 3)
  ushort* ctxT = (ushort*)logits;        // overlays logits (dead after softmax)
  const long TRIB = (long)NTRI * TRI_ELEMS;
  const long XB = XE / BB;

  prep<<<dim3(64, 32, 6), dim3(32, 8), 0, stream>>>(
      x, WQ, WK, WV, WO, x_hi, xTh, xTl,
      wqT_h, wqT_l, wkT_h, wkT_l, wvT_h, woT_h);

  // Mqk (split) + Mov (plain), merged 64-tile dispatch
  gemm_w<<<dim3(512), 256, 16384, stream>>>(
      wqT_h, wqT_l, wkT_h, wkT_l, wvT_h, woT_h, mqk_h, mqk_l, mov_h);

  // tT = xT * Mqk^T (8-phase regime, 256x128 tiles, split-as-K=3072)
  gemm8<0><<<dim3(256), dim3(512), 0, stream>>>(
      xTh, xTl, mqk_h, mqk_l, tTh, tTl,
      DD, DD, DD, XB, 0, XB);

  // logits (lower tri, 8-phase regime, 288 blocks)
  gemm8<1><<<dim3(288), dim3(512), 0, stream>>>(
      xTh, xTl, tTh, tTl, logits, nullptr,
      DD, DD, 0, XB, XB, TRIB);

  softmax_tri<<<dim3(BB * NN), 256, 0, stream>>>(logits, A_tri);

  // ctxT = A * x^T (tri A, causal K-limit, balanced XCD swizzle, dbuf)
  gemm_mfma<1, 2, 3><<<dim3(512), 256, 65536, stream>>>(
      A_tri, x_hi, ctxT, nullptr,
      NN, 0, NN, DD, TRIB, XB, XB, 0);

  // out = x + Mov * ctx (SWIZ=4: M=8 d-tiles, N=16 i-tiles, dbuf)
  gemm_mfma<0, 3, 4><<<dim3(512), 256, 65536, stream>>>(
      mov_h, ctxT, out, x,
      DD, DD, DD, NN, 0, XB, XB, XB);
}

// Round 8
// 314.722 us; speedup vs baseline: 1.1085x; 1.0785x over previous
//
#include <hip/hip_runtime.h>
#include <hip/hip_bf16.h>
#include <math.h>

// Problem constants: B=4, D=1024, N=2048, K=1024, fp32 in/out.
#define BB 4
#define DD 1024
#define NN 2048
#define KK 1024
#define NT128 16            // NN/128
#define NTRI 136            // 16*17/2 lower-triangular 128x128 tiles
#define TRI_ELEMS 16384     // 128*128

typedef __attribute__((ext_vector_type(4))) float f32x4;
typedef __attribute__((ext_vector_type(8))) short bfrag;

typedef __attribute__((address_space(1))) const unsigned int gu32;
typedef __attribute__((address_space(3))) unsigned int lu32;

// async global->LDS, 16B per lane; LDS dest = base + lane*16 (wave-uniform base)
__device__ __forceinline__ void async16(const void* g, void* l) {
  __builtin_amdgcn_global_load_lds((gu32*)g, (lu32*)l, 16, 0, 0);
}

__device__ __forceinline__ ushort f2b(float f) {  // fp32 -> bf16 RNE
  union { float f; unsigned u; } c; c.f = f;
  unsigned u = c.u + 0x7fffu + ((c.u >> 16) & 1u);
  return (ushort)(u >> 16);
}
__device__ __forceinline__ float b2f(ushort h) {
  union { unsigned u; float f; } c; c.u = ((unsigned)h) << 16;
  return c.f;
}

// ---------------------------------------------------------------------------
// prep: merged input transform, grid (64, 32, 6), block (32,8).
//  z<4 : x [b=z][d][n] fp32 -> x_hi (bf16 same layout), xT hi/lo ([b][n][d])
//        R8: float4 loads + ushort4 stores (G13), one pass per 32x32 tile.
//  z>=4: weight w = (z-4)*2 + (bx>>5): W (K x D, [k][d]) -> WT [d][k] bf16
//        (WQ, WK split hi+lo; WV, WO hi only) -- unchanged scalar path.
// ---------------------------------------------------------------------------
__global__ __launch_bounds__(256) void prep(
    const float* __restrict__ x,
    const float* __restrict__ WQ, const float* __restrict__ WK,
    const float* __restrict__ WV, const float* __restrict__ WO,
    ushort* __restrict__ xhi, ushort* __restrict__ xTh, ushort* __restrict__ xTl,
    ushort* __restrict__ qh, ushort* __restrict__ ql,
    ushort* __restrict__ kh, ushort* __restrict__ kl_,
    ushort* __restrict__ vh, ushort* __restrict__ oh) {
  const int z = blockIdx.z;
  const int tx = threadIdx.x, ty = threadIdx.y;
  __shared__ float tile[32][33];
  if (z < 4) {
    const int b = z;
    const int n0 = blockIdx.x * 32, d0 = blockIdx.y * 32;
    const float* xb = x + (long)b * DD * NN;
    ushort* xhb = xhi + (long)b * DD * NN;
    const int tid = ty * 32 + tx;
    // load phase: 256 threads cover 32 d-rows x 8 float4 (32 n-cols)
    const int dl = tid >> 3, c4 = (tid & 7) * 4;
    const float4 v4 = *(const float4*)&xb[(long)(d0 + dl) * NN + n0 + c4];
    tile[dl][c4 + 0] = v4.x; tile[dl][c4 + 1] = v4.y;
    tile[dl][c4 + 2] = v4.z; tile[dl][c4 + 3] = v4.w;
    ushort4 h4;
    h4.x = f2b(v4.x); h4.y = f2b(v4.y); h4.z = f2b(v4.z); h4.w = f2b(v4.w);
    *(ushort4*)&xhb[(long)(d0 + dl) * NN + n0 + c4] = h4;
    __syncthreads();
    // transpose phase: each thread emits 4 consecutive d for one n (ushort4)
    const int nl = tid >> 3, d4 = (tid & 7) * 4;
    const float w0 = tile[d4 + 0][nl], w1 = tile[d4 + 1][nl];
    const float w2 = tile[d4 + 2][nl], w3 = tile[d4 + 3][nl];
    ushort4 hh, ll;
    hh.x = f2b(w0); ll.x = f2b(w0 - b2f(hh.x));
    hh.y = f2b(w1); ll.y = f2b(w1 - b2f(hh.y));
    hh.z = f2b(w2); ll.z = f2b(w2 - b2f(hh.z));
    hh.w = f2b(w3); ll.w = f2b(w3 - b2f(hh.w));
    const long o = (long)b * NN * DD + (long)(n0 + nl) * DD + d0 + d4;
    *(ushort4*)&xTh[o] = hh;
    *(ushort4*)&xTl[o] = ll;
  } else {
    const int w = (z - 4) * 2 + (blockIdx.x >> 5);
    const float* W = (w == 0) ? WQ : (w == 1) ? WK : (w == 2) ? WV : WO;
    ushort* Th = (w == 0) ? qh : (w == 1) ? kh : (w == 2) ? vh : oh;
    ushort* Tl = (w == 0) ? ql : (w == 1) ? kl_ : nullptr;
    const int k0 = (blockIdx.x & 31) * 32, d0 = blockIdx.y * 32;
#pragma unroll
    for (int r = 0; r < 4; ++r) {
      const int kl = ty + r * 8;
      tile[kl][tx] = W[(long)(k0 + kl) * DD + d0 + tx];
    }
    __syncthreads();
#pragma unroll
    for (int r = 0; r < 4; ++r) {
      const int dl = ty + r * 8;
      const float v = tile[tx][dl];              // = W[k0+tx][d0+dl]
      const ushort h = f2b(v);
      const long o = (long)(d0 + dl) * KK + k0 + tx;
      Th[o] = h;
      if (Tl) Tl[o] = f2b(v - b2f(h));
    }
  }
}

// ---------------------------------------------------------------------------
// Merged weight-product GEMM, 64x64 tiles, BK=32, 512 blocks:
//   id<256 : Mqk[m,n] = sum_k wqT[m,k] wkT[n,k]  (split 3-MFMA, split store)
//   id>=256: Mov[m,n] = sum_k woT[m,k] wvT[n,k]  (plain bf16)
// ---------------------------------------------------------------------------
__global__ __launch_bounds__(256) void gemm_w(
    const ushort* __restrict__ qh, const ushort* __restrict__ ql,
    const ushort* __restrict__ kh, const ushort* __restrict__ kl_,
    const ushort* __restrict__ vh, const ushort* __restrict__ oh,
    ushort* __restrict__ mqk_h, ushort* __restrict__ mqk_l,
    ushort* __restrict__ mov_h) {
  extern __shared__ ushort smem[];
  ushort* sAh = smem;            // [64][32] 4KB
  ushort* sAl = smem + 2048;
  ushort* sBh = smem + 4096;
  ushort* sBl = smem + 6144;

  const int id = blockIdx.x;
  const int half = id >> 8;                  // 0 = Mqk (split), 1 = Mov (plain)
  const int t = id & 255;
  const int m0 = (t >> 4) * 64, n0 = (t & 15) * 64;
  const ushort* A_h = half ? oh : qh;
  const ushort* B_h = half ? vh : kh;

  const int tid = threadIdx.x;
  const int lane = tid & 63, wave = tid >> 6;
  const int wm = (wave & 1) * 32, wn = (wave >> 1) * 32;
  const int r16 = lane & 15, quad = lane >> 4;
  const int kc = ((lane & 3) ^ ((lane >> 3) & 3)) * 8;   // swizzled k-chunk
  const int srow = lane >> 2;

  f32x4 acc[2][2];
#pragma unroll
  for (int i = 0; i < 2; ++i)
#pragma unroll
    for (int j = 0; j < 2; ++j) acc[i][j] = (f32x4){0.f, 0.f, 0.f, 0.f};

  for (int k0 = 0; k0 < KK; k0 += 32) {
    __syncthreads();
    {
      const int row = wave * 16 + srow;
      const long aoff = (long)(m0 + row) * KK + k0 + kc;
      const long boff = (long)(n0 + row) * KK + k0 + kc;
      async16(A_h + aoff, sAh + wave * 512);
      async16(B_h + boff, sBh + wave * 512);
      if (half == 0) {
        async16(ql + aoff, sAl + wave * 512);
        async16(kl_ + boff, sBl + wave * 512);
      }
    }
    __syncthreads();

    const int sw = (r16 >> 1) & 3;
    bfrag ah[2], bh[2], al[2], bl[2];
#pragma unroll
    for (int t2 = 0; t2 < 2; ++t2) {
      ah[t2] = *(const bfrag*)&sAh[(wm + t2 * 16 + r16) * 32 + (quad ^ sw) * 8];
      bh[t2] = *(const bfrag*)&sBh[(wn + t2 * 16 + r16) * 32 + (quad ^ sw) * 8];
      if (half == 0) {
        al[t2] = *(const bfrag*)&sAl[(wm + t2 * 16 + r16) * 32 + (quad ^ sw) * 8];
        bl[t2] = *(const bfrag*)&sBl[(wn + t2 * 16 + r16) * 32 + (quad ^ sw) * 8];
      }
    }
#pragma unroll
    for (int mt = 0; mt < 2; ++mt)
#pragma unroll
      for (int nt = 0; nt < 2; ++nt) {
        acc[mt][nt] = __builtin_amdgcn_mfma_f32_16x16x32_bf16(ah[mt], bh[nt], acc[mt][nt], 0, 0, 0);
        if (half == 0) {
          acc[mt][nt] = __builtin_amdgcn_mfma_f32_16x16x32_bf16(ah[mt], bl[nt], acc[mt][nt], 0, 0, 0);
          acc[mt][nt] = __builtin_amdgcn_mfma_f32_16x16x32_bf16(al[mt], bh[nt], acc[mt][nt], 0, 0, 0);
        }
      }
  }

#pragma unroll
  for (int mt = 0; mt < 2; ++mt)
#pragma unroll
    for (int nt = 0; nt < 2; ++nt)
#pragma unroll
      for (int reg = 0; reg < 4; ++reg) {
        const int ml = wm + mt * 16 + quad * 4 + reg;
        const int nl = wn + nt * 16 + r16;
        const float v = acc[mt][nt][reg];
        const long o = (long)(m0 + ml) * DD + n0 + nl;
        if (half == 0) {
          const ushort h = f2b(v);
          mqk_h[o] = h;
          mqk_l[o] = f2b(v - b2f(h));
        } else {
          mov_h[o] = f2b(v);
        }
      }
}

// ---------------------------------------------------------------------------
// bf16 MFMA GEMM (R4-exact, best measured): 128x128 block tile, 4 waves
// (2x2) of 64x64, recipe dbuf schedule (STAGE(t+1) issued BEFORE compute,
// ONE vmcnt(0)+barrier per tile AFTER the MFMAs), ^(row&7) chunk swizzle
// realized via pre-swizzled global source (0 conflicts, R2-R5 measured).
// SPLIT=1: BK=32, hi|lo packed per 128B row (chunks 0-3 = hi k, 4-7 = lo).
// SPLIT=0: BK=64, chunks = k-chunks.
// Fragment layouts (HW-verified, learn_hip m89):
//   A[m=lane&15][k=quad*8+j], B[n=lane&15][k=quad*8+j],
//   C/D: col=lane&15, row=quad*4+reg.
// TRIA : A staged from triangular tile layout; K limited to m0+128.
// SWIZ : XCD-locality block mapping (assumes xcd = blockIdx.x % 8):
//   1: 512 blocks, (b, m0)=P, n0: M=16 tiles, N=8 tiles
//   2: 544 blocks (logits tri), g=(blk&7)*68+(blk>>3); b=g/136, t=g%136
//   3: 512 blocks, causal-balanced: XCD x owns mtiles {x, 15-x}
//   4: 512 blocks, swapped roles (M=8 d-tiles, N=16 i-tiles)
// STORE 0: split bf16 (C0=hi, C1=lo); 1: tri fp32; 2: bf16; 3: fp32 + Res.
// ---------------------------------------------------------------------------
template <int SPLIT, int TRIA, int STORE, int SWIZ>
__global__ __launch_bounds__(256) void gemm_mfma(
    const ushort* __restrict__ Ah, const ushort* __restrict__ Al,
    const ushort* __restrict__ Bh, const ushort* __restrict__ Bl,
    void* __restrict__ C0, void* __restrict__ C1, const float* __restrict__ Res,
    int K, int lda, int ldb, int ldc,
    long bA, long bB, long bC, long bR) {
  extern __shared__ ushort smem[];   // 2 x 16384 ushorts (sA 8192 | sB 8192)

  int b, m0, n0, tiC = 0;
  if (SWIZ == 2) {
    const int g = (blockIdx.x & 7) * 68 + (blockIdx.x >> 3);
    b = g / NTRI;
    int t = g - b * NTRI;
    int ti = 0;
    while ((ti + 1) * (ti + 2) / 2 <= t) ++ti;
    const int tj = t - ti * (ti + 1) / 2;
    m0 = ti * 128; n0 = tj * 128; tiC = t;
  } else if (SWIZ == 1) {
    const int g = (blockIdx.x & 7) * 64 + (blockIdx.x >> 3);
    const int P = g >> 3;
    b = P >> 4;
    m0 = (P & 15) * 128;
    n0 = (g & 7) * 128;
  } else if (SWIZ == 3) {
    const int xcd = blockIdx.x & 7;
    const int idx = blockIdx.x >> 3;      // [0,64)
    const int q = idx >> 3;               // [0,8)
    b = q >> 1;
    const int mt_ = (q & 1) ? (15 - xcd) : xcd;
    m0 = mt_ * 128;
    n0 = (idx & 7) * 128;
  } else {  // SWIZ == 4
    const int g = (blockIdx.x & 7) * 64 + (blockIdx.x >> 3);
    const int P = g >> 3;
    b = P >> 4;
    n0 = (P & 15) * 128;
    m0 = (g & 7) * 128;
  }
  const int kmax = TRIA ? (m0 + 128) : K;
  int triA0 = 0;
  if (TRIA) { const int ti = m0 >> 7; triA0 = ti * (ti + 1) / 2; }

  const ushort* A_h = Ah + (long)b * bA;
  const ushort* B_h = Bh + (long)b * bB;
  const ushort* A_l = SPLIT ? Al + (long)b * bA : nullptr;
  const ushort* B_l = SPLIT ? Bl + (long)b * bB : nullptr;

  const int tid = threadIdx.x;
  const int lane = tid & 63, wave = tid >> 6;
  const int wm = (wave & 1) * 64, wn = (wave >> 1) * 64;
  const int r16 = lane & 15, quad = lane >> 4;
  const int rk = r16 & 7;

  // staging lane mapping: 8 rows x 8 phys chunks per async16 (1KB)
  const int lrow = lane >> 3;                  // row within 8-row segment
  const int lc = (lane & 7) ^ lrow;            // logical chunk = phys ^ row&7
  // SPLIT: logical chunks 0-3 = hi k-chunks, 4-7 = lo k-chunks
  const int lckS = (lc & 3) * 8;
  const bool lo_src = lc >= 4;
  // plain: logical chunk = k-chunk of BK=64
  const int kcP = lc * 8;

  f32x4 acc[4][4];
#pragma unroll
  for (int i = 0; i < 4; ++i)
#pragma unroll
    for (int j = 0; j < 4; ++j) acc[i][j] = (f32x4){0.f, 0.f, 0.f, 0.f};

  auto STAGE = [&](int db, int t) {
    ushort* dst = smem + db * 16384;
    if (SPLIT) {
      const int k0 = t << 5;
#pragma unroll
      for (int s = 0; s < 4; ++s) {
        const int seg = wave * 4 + s;          // [0,16): 8-row group
        const int row = seg * 8 + lrow;        // [0,128)
        const ushort* baseA = lo_src ? A_l : A_h;
        const ushort* baseB = lo_src ? B_l : B_h;
        async16(baseA + (long)(m0 + row) * lda + k0 + lckS, dst + seg * 512);
        async16(baseB + (long)(n0 + row) * ldb + k0 + lckS, dst + 8192 + seg * 512);
      }
    } else {
      const int k0 = t << 6;
#pragma unroll
      for (int s = 0; s < 4; ++s) {
        const int seg = wave * 4 + s;
        const int row = seg * 8 + lrow;
        long aoff;
        if (TRIA)
          aoff = (long)(triA0 + (k0 >> 7)) * TRI_ELEMS + (long)row * 128 + (k0 & 127) + kcP;
        else
          aoff = (long)(m0 + row) * lda + k0 + kcP;
        async16(A_h + aoff, dst + seg * 512);
        async16(B_h + (long)(n0 + row) * ldb + k0 + kcP, dst + 8192 + seg * 512);
      }
    }
  };

  const int T = kmax >> (SPLIT ? 5 : 6);
  STAGE(0, 0);
  asm volatile("s_waitcnt vmcnt(0)" ::: "memory");
  __builtin_amdgcn_s_barrier();
  __builtin_amdgcn_sched_barrier(0);

  for (int t = 0; t < T; ++t) {
    const int cur = t & 1;
    if (t + 1 < T) STAGE(cur ^ 1, t + 1);      // issue BEFORE compute
    const ushort* sA = smem + cur * 16384;
    const ushort* sB = sA + 8192;

    if (SPLIT) {
      bfrag ah[4], al[4], bh[4], bl[4];
#pragma unroll
      for (int f = 0; f < 4; ++f) {
        const int arow = (wm + f * 16 + r16) * 64;
        const int brow = (wn + f * 16 + r16) * 64;
        ah[f] = *(const bfrag*)&sA[arow + (quad ^ rk) * 8];
        al[f] = *(const bfrag*)&sA[arow + ((quad + 4) ^ rk) * 8];
        bh[f] = *(const bfrag*)&sB[brow + (quad ^ rk) * 8];
        bl[f] = *(const bfrag*)&sB[brow + ((quad + 4) ^ rk) * 8];
      }
      __builtin_amdgcn_s_setprio(1);
#pragma unroll
      for (int mt = 0; mt < 4; ++mt)
#pragma unroll
        for (int nt = 0; nt < 4; ++nt) {
          acc[mt][nt] = __builtin_amdgcn_mfma_f32_16x16x32_bf16(ah[mt], bh[nt], acc[mt][nt], 0, 0, 0);
          acc[mt][nt] = __builtin_amdgcn_mfma_f32_16x16x32_bf16(ah[mt], bl[nt], acc[mt][nt], 0, 0, 0);
          acc[mt][nt] = __builtin_amdgcn_mfma_f32_16x16x32_bf16(al[mt], bh[nt], acc[mt][nt], 0, 0, 0);
        }
      __builtin_amdgcn_s_setprio(0);
    } else {
#pragma unroll
      for (int ksub = 0; ksub < 2; ++ksub) {
        const int ch = ((ksub * 4 + quad) ^ rk) * 8;     // physical chunk
        bfrag a4[4], b4[4];
#pragma unroll
        for (int f = 0; f < 4; ++f) {
          a4[f] = *(const bfrag*)&sA[(wm + f * 16 + r16) * 64 + ch];
          b4[f] = *(const bfrag*)&sB[(wn + f * 16 + r16) * 64 + ch];
        }
        __builtin_amdgcn_s_setprio(1);
#pragma unroll
        for (int mt = 0; mt < 4; ++mt)
#pragma unroll
          for (int nt = 0; nt < 4; ++nt)
            acc[mt][nt] = __builtin_amdgcn_mfma_f32_16x16x32_bf16(a4[mt], b4[nt], acc[mt][nt], 0, 0, 0);
        __builtin_amdgcn_s_setprio(0);
      }
    }

    __builtin_amdgcn_sched_barrier(0);
    asm volatile("s_waitcnt vmcnt(0)" ::: "memory");   // t+1 loads landed
    __builtin_amdgcn_s_barrier();                      // buf[cur^1] ready
    __builtin_amdgcn_sched_barrier(0);
  }

  // epilogue
#pragma unroll
  for (int mt = 0; mt < 4; ++mt)
#pragma unroll
    for (int nt = 0; nt < 4; ++nt)
#pragma unroll
      for (int reg = 0; reg < 4; ++reg) {
        const int ml = wm + mt * 16 + quad * 4 + reg;
        const int nl = wn + nt * 16 + r16;
        const float v = acc[mt][nt][reg];
        if (STORE == 0) {
          ushort* Ch = (ushort*)C0 + (long)b * bC;
          ushort* Cl = (ushort*)C1 + (long)b * bC;
          const long o = (long)(m0 + ml) * ldc + n0 + nl;
          const ushort h = f2b(v);
          Ch[o] = h;
          Cl[o] = f2b(v - b2f(h));
        } else if (STORE == 1) {
          float* C = (float*)C0 + (long)b * bC + (long)tiC * TRI_ELEMS;
          C[ml * 128 + nl] = v;
        } else if (STORE == 2) {
          ushort* C = (ushort*)C0 + (long)b * bC;
          C[(long)(m0 + ml) * ldc + n0 + nl] = f2b(v);
        } else {
          float* C = (float*)C0 + (long)b * bC;
          const float* R = Res + (long)b * bR;
          const long o = (long)(m0 + ml) * ldc + n0 + nl;
          C[o] = R[o] + v;
        }
      }
}

// ---------------------------------------------------------------------------
// Causal softmax over triangular-tiled logits. One block per row (b, i).
// R8: float4 logit loads + ushort4 A-stores (G13). Cols in [len, tot) within
// stored tiles hold finite garbage (step 3 writes full 128x128 tiles for
// jt<=ti) -> safe to load, masked with -INF / zero.
// ---------------------------------------------------------------------------
__global__ __launch_bounds__(256) void softmax_tri(
    const float* __restrict__ L, ushort* __restrict__ Aout) {
  const int row = blockIdx.x;
  const int b = row >> 11, i = row & (NN - 1);
  const int ti = i >> 7, ml = i & 127;
  const long base = (long)b * ((long)NTRI * TRI_ELEMS);
  const int trib = ti * (ti + 1) / 2;
  const int len = i + 1;
  const int tot = (ti + 1) * 128;
  const int tid = threadIdx.x;
  __shared__ float red[256];
  float vv[8];
  float m = -INFINITY;
#pragma unroll
  for (int u = 0; u < 2; ++u) {
    const int j = (tid + u * 256) * 4;
    if (j < tot) {
      const long o = base + (long)(trib + (j >> 7)) * TRI_ELEMS + ml * 128 + (j & 127);
      const float4 v = *(const float4*)&L[o];
      vv[u * 4 + 0] = v.x; vv[u * 4 + 1] = v.y;
      vv[u * 4 + 2] = v.z; vv[u * 4 + 3] = v.w;
#pragma unroll
      for (int e = 0; e < 4; ++e)
        if (j + e < len) m = fmaxf(m, vv[u * 4 + e]);
    }
  }
  red[tid] = m; __syncthreads();
  for (int s = 128; s; s >>= 1) { if (tid < s) red[tid] = fmaxf(red[tid], red[tid + s]); __syncthreads(); }
  m = red[0]; __syncthreads();
  float sum = 0.f;
#pragma unroll
  for (int u = 0; u < 2; ++u) {
    const int j = (tid + u * 256) * 4;
#pragma unroll
    for (int e = 0; e < 4; ++e) {
      if (j + e < len) { const float ex = __expf(vv[u * 4 + e] - m); vv[u * 4 + e] = ex; sum += ex; }
      else vv[u * 4 + e] = 0.f;
    }
  }
  red[tid] = sum; __syncthreads();
  for (int s = 128; s; s >>= 1) { if (tid < s) red[tid] += red[tid + s]; __syncthreads(); }
  const float inv = 1.f / red[0];
#pragma unroll
  for (int u = 0; u < 2; ++u) {
    const int j = (tid + u * 256) * 4;
    if (j < tot) {
      ushort4 o4;
      o4.x = (j + 0 < len) ? f2b(vv[u * 4 + 0] * inv) : (ushort)0;
      o4.y = (j + 1 < len) ? f2b(vv[u * 4 + 1] * inv) : (ushort)0;
      o4.z = (j + 2 < len) ? f2b(vv[u * 4 + 2] * inv) : (ushort)0;
      o4.w = (j + 3 < len) ? f2b(vv[u * 4 + 3] * inv) : (ushort)0;
      const long o = base + (long)(trib + (j >> 7)) * TRI_ELEMS + ml * 128 + (j & 127);
      *(ushort4*)&Aout[o] = o4;
    }
  }
}

// ---------------------------------------------------------------------------
// Pipeline (all MFMA operands k-contiguous by construction):
//  0. prep: x -> x_hi, xT hi/lo; W_Q..W_O -> WT [d][k] bf16     (1 dispatch)
//  1. gemm_w: Mqk (split) + Mov (plain) in one 512-block dispatch
//  2. tT[i,d] = sum_e xT[i,e] Mqk[d,e]      split, SWIZ=1, 512 blocks
//  3. logits[i,j] = sum_d xT[i,d] tT[j,d]   split, tri tiles, SWIZ=2, 544
//  4. A = causal softmax (bf16, tri layout, zero-padded diag tiles)
//  5. ctxT[i,e] = sum_{t<=i} A[i,t] x[e,t]  plain, causal K, SWIZ=3 (bal)
//  6. out[d,i] = x[d,i] + sum_e Mov[d,e] ctxT[i,e]   plain + res, SWIZ=4
// ---------------------------------------------------------------------------
extern "C" void kernel_launch(void* const* d_in, const int* in_sizes, int n_in,
                              void* d_out, int out_size, void* d_ws, size_t ws_size,
                              hipStream_t stream) {
  const float* x = (const float*)d_in[0];
  const float* WQ = (const float*)d_in[1];
  const float* WK = (const float*)d_in[2];
  const float* WV = (const float*)d_in[3];
  const float* WO = (const float*)d_in[4];
  float* out = (float*)d_out;

  const long XE = (long)BB * DD * NN;    // 8M elements
  const long WE = (long)DD * KK;         // 1M elements
  ushort* x_hi = (ushort*)d_ws;
  ushort* xTh = x_hi + XE;
  ushort* xTl = xTh + XE;
  ushort* wqT_h = xTl + XE;
  ushort* wqT_l = wqT_h + WE;
  ushort* wkT_h = wqT_l + WE;
  ushort* wkT_l = wkT_h + WE;
  ushort* wvT_h = wkT_l + WE;
  ushort* woT_h = wvT_h + WE;
  ushort* mqk_h = woT_h + WE;
  ushort* mqk_l = mqk_h + WE;
  ushort* mov_h = mqk_l + WE;
  ushort* tTh = mov_h + WE;
  ushort* tTl = tTh + XE;
  float* logits = (float*)(tTl + XE);    // B*NTRI*TRI_ELEMS fp32 (~35.7MB)
  ushort* A_tri = tTh;                   // overlays tT hi+lo (dead after step 3)
  ushort* ctxT = (ushort*)logits;        // overlays logits (dead after softmax)
  const long TRIB = (long)NTRI * TRI_ELEMS;
  const long XB = XE / BB;

  prep<<<dim3(64, 32, 6), dim3(32, 8), 0, stream>>>(
      x, WQ, WK, WV, WO, x_hi, xTh, xTl,
      wqT_h, wqT_l, wkT_h, wkT_l, wvT_h, woT_h);

  // Mqk (split) + Mov (plain), merged 64-tile dispatch
  gemm_w<<<dim3(512), 256, 16384, stream>>>(
      wqT_h, wqT_l, wkT_h, wkT_l, wvT_h, woT_h, mqk_h, mqk_l, mov_h);

  // tT = xT * Mqk^T (split, recipe dbuf BK=32, 64KB LDS, 2 blk/CU)
  gemm_mfma<1, 0, 0, 1><<<dim3(512), 256, 65536, stream>>>(
      xTh, xTl, mqk_h, mqk_l, tTh, tTl, nullptr,
      DD, DD, DD, DD, XB, 0, XB, 0);

  // logits (lower tri tiles, split recipe dbuf)
  gemm_mfma<1, 0, 1, 2><<<dim3(BB * NTRI), 256, 65536, stream>>>(
      xTh, xTl, tTh, tTl, logits, nullptr, nullptr,
      DD, DD, DD, 0, XB, XB, TRIB, 0);

  softmax_tri<<<dim3(BB * NN), 256, 0, stream>>>(logits, A_tri);

  // ctxT = A * x^T (tri A, causal K-limit, balanced XCD swizzle, dbuf)
  gemm_mfma<0, 1, 2, 3><<<dim3(512), 256, 65536, stream>>>(
      A_tri, nullptr, x_hi, nullptr, ctxT, nullptr, nullptr,
      NN, 0, NN, DD, TRIB, XB, XB, 0);

  // out = x + Mov * ctx (SWIZ=4: M=8 d-tiles, N=16 i-tiles, dbuf)
  gemm_mfma<0, 0, 3, 4><<<dim3(512), 256, 65536, stream>>>(
      mov_h, nullptr, ctxT, nullptr, out, nullptr, x,
      DD, DD, DD, NN, 0, XB, XB, XB);
}